// Round 1
// baseline (2162.423 us; speedup 1.0000x reference)
//
#include <hip/hip_runtime.h>
#include <math.h>

#define N 4096
#define NF 512
#define NH 128
#define NC 16

// ---------------------------------------------------------------------------
// k_wc: Wc_k[j,c] = sum_t Wa_k[j,t] * Wagg[k*64+t, c]   (3*N*3 values)
//       bz[c] = bagg[c] + sum_t ba1[t]*Wagg[t,c] + ba2[t]*Wagg[64+t,c] + ...
// ---------------------------------------------------------------------------
__global__ void k_wc(const float* __restrict__ Wa1, const float* __restrict__ Wa2,
                     const float* __restrict__ Wa3, const float* __restrict__ Wagg,
                     const float* __restrict__ ba1, const float* __restrict__ ba2,
                     const float* __restrict__ ba3, const float* __restrict__ bagg,
                     float* __restrict__ Wc, float* __restrict__ bz) {
  int idx = blockIdx.x * 256 + threadIdx.x;
  if (idx < 3 * N) {
    int k = idx >> 12;            // /N
    int j = idx & (N - 1);
    const float* Wa = (k == 0) ? Wa1 : (k == 1) ? Wa2 : Wa3;
    float a0 = 0.f, a1 = 0.f, a2 = 0.f;
    for (int t = 0; t < 64; ++t) {
      float w = Wa[j * 64 + t];
      const float* wg = Wagg + (k * 64 + t) * 3;
      a0 += w * wg[0]; a1 += w * wg[1]; a2 += w * wg[2];
    }
    float* o = Wc + j * 9 + k * 3;   // layout [j][k][c]
    o[0] = a0; o[1] = a1; o[2] = a2;
  }
  if (blockIdx.x == 0 && threadIdx.x < 3) {
    int c = threadIdx.x;
    float acc = bagg[c];
    for (int t = 0; t < 64; ++t) {
      acc += ba1[t] * Wagg[t * 3 + c]
           + ba2[t] * Wagg[(64 + t) * 3 + c]
           + ba3[t] * Wagg[(128 + t) * 3 + c];
    }
    bz[c] = acc;
  }
}

// ---------------------------------------------------------------------------
// k_z4nz: z4[i,c] = sum_j (A0[i,j]*Wc0[j,c] + A1[i,j]*Wc1[j,c] + A2[i,j]*Wc2[j,c]) + bz[c]
//         nz = softmax(z4 rows of 3).  16 rows per block, 256 threads.
// ---------------------------------------------------------------------------
__global__ void k_z4nz(const float* __restrict__ A0, const float* __restrict__ A1,
                       const float* __restrict__ A2, const float* __restrict__ Wc,
                       const float* __restrict__ bz, float* __restrict__ nz) {
  __shared__ float red[16][3][4];
  int i0 = blockIdx.x * 16;
  int tid = threadIdx.x;
  float acc[16][3];
#pragma unroll
  for (int r = 0; r < 16; ++r) { acc[r][0] = 0.f; acc[r][1] = 0.f; acc[r][2] = 0.f; }
  for (int j = tid; j < N; j += 256) {
    const float* w = Wc + j * 9;
    float w0 = w[0], w1 = w[1], w2 = w[2], w3 = w[3], w4 = w[4];
    float w5 = w[5], w6 = w[6], w7 = w[7], w8 = w[8];
#pragma unroll
    for (int r = 0; r < 16; ++r) {
      float a0 = A0[(i0 + r) * N + j];
      float a1 = A1[(i0 + r) * N + j];
      float a2 = A2[(i0 + r) * N + j];
      acc[r][0] += a0 * w0 + a1 * w3 + a2 * w6;
      acc[r][1] += a0 * w1 + a1 * w4 + a2 * w7;
      acc[r][2] += a0 * w2 + a1 * w5 + a2 * w8;
    }
  }
  int lane = tid & 63, wv = tid >> 6;
#pragma unroll
  for (int r = 0; r < 16; ++r) {
#pragma unroll
    for (int c = 0; c < 3; ++c) {
      float v = acc[r][c];
      for (int off = 32; off > 0; off >>= 1) v += __shfl_down(v, off);
      if (lane == 0) red[r][c][wv] = v;
    }
  }
  __syncthreads();
  if (tid < 16) {
    float z0 = red[tid][0][0] + red[tid][0][1] + red[tid][0][2] + red[tid][0][3] + bz[0];
    float z1 = red[tid][1][0] + red[tid][1][1] + red[tid][1][2] + red[tid][1][3] + bz[1];
    float z2 = red[tid][2][0] + red[tid][2][1] + red[tid][2][2] + red[tid][2][3] + bz[2];
    float m = fmaxf(z0, fmaxf(z1, z2));
    float e0 = expf(z0 - m), e1 = expf(z1 - m), e2 = expf(z2 - m);
    float s = e0 + e1 + e2;
    float* o = nz + (i0 + tid) * 3;
    o[0] = e0 / s; o[1] = e1 / s; o[2] = e2 / s;
  }
}

// ---------------------------------------------------------------------------
// k_adj: adj[i,j] = A0[i,j]*nz[j,0] + A1[i,j]*nz[j,1] + A2[i,j]*nz[j,2]
//        (torch-style broadcasting: nz indexed by COLUMN j). float4 vectorized.
// ---------------------------------------------------------------------------
__global__ void k_adj(const float* __restrict__ A0, const float* __restrict__ A1,
                      const float* __restrict__ A2, const float* __restrict__ nz,
                      float* __restrict__ adj) {
  int idx = blockIdx.x * 256 + threadIdx.x;       // float4 index, N*N/4 total
  int i = idx >> 10;
  int j4 = (idx & 1023) << 2;
  int base = i * N + j4;
  const float4 a0 = *(const float4*)&A0[base];
  const float4 a1 = *(const float4*)&A1[base];
  const float4 a2 = *(const float4*)&A2[base];
  const float4 n0 = *(const float4*)&nz[j4 * 3];
  const float4 n1 = *(const float4*)&nz[j4 * 3 + 4];
  const float4 n2 = *(const float4*)&nz[j4 * 3 + 8];
  float4 o;
  o.x = a0.x * n0.x + a1.x * n0.y + a2.x * n0.z;
  o.y = a0.y * n0.w + a1.y * n1.x + a2.y * n1.y;
  o.z = a0.z * n1.z + a1.z * n1.w + a2.z * n2.x;
  o.w = a0.w * n2.y + a1.w * n2.z + a2.w * n2.w;
  *(float4*)&adj[base] = o;
}

// ---------------------------------------------------------------------------
// k_xw1: xw1 = x @ W1   ([N,512]@[512,128]); 16 rows/block, 128 threads
// ---------------------------------------------------------------------------
__global__ void k_xw1(const float* __restrict__ x, const float* __restrict__ W1,
                      float* __restrict__ xw1) {
  __shared__ float xs[16][NF];
  int i0 = blockIdx.x * 16;
  int tid = threadIdx.x;
  for (int l = tid; l < 16 * NF; l += 128) {
    int r = l >> 9, k = l & (NF - 1);
    xs[r][k] = x[(i0 + r) * NF + k];
  }
  __syncthreads();
  float acc[16];
#pragma unroll
  for (int r = 0; r < 16; ++r) acc[r] = 0.f;
  for (int k = 0; k < NF; ++k) {
    float w = W1[k * NH + tid];
#pragma unroll
    for (int r = 0; r < 16; ++r) acc[r] += xs[r][k] * w;
  }
  for (int r = 0; r < 16; ++r) xw1[(i0 + r) * NH + tid] = acc[r];
}

// hpre init with bias b1 (atomics accumulate on top)
__global__ void k_hinit(const float* __restrict__ b1, float* __restrict__ hpre) {
  int idx = blockIdx.x * 256 + threadIdx.x;
  if (idx < N * NH) hpre[idx] = b1[idx & (NH - 1)];
}

// ---------------------------------------------------------------------------
// k_h: hpre += adj @ xw1  (split-K over grid.y=8, atomicAdd). relu applied in k_qkv.
//      16 rows/block, 128 threads (one per output column).
// ---------------------------------------------------------------------------
__global__ void k_h(const float* __restrict__ adj, const float* __restrict__ xw1,
                    float* __restrict__ hpre) {
  __shared__ float as[16][256];
  int i0 = blockIdx.x * 16;
  int k0 = blockIdx.y * 512;
  int tid = threadIdx.x;
  float acc[16];
#pragma unroll
  for (int r = 0; r < 16; ++r) acc[r] = 0.f;
  for (int kc = 0; kc < 512; kc += 256) {
    for (int l = tid; l < 16 * 256; l += 128) {
      int r = l >> 8, kk = l & 255;
      as[r][kk] = adj[(i0 + r) * N + k0 + kc + kk];
    }
    __syncthreads();
    for (int kk = 0; kk < 256; kk += 4) {
      float w0 = xw1[(k0 + kc + kk + 0) * NH + tid];
      float w1 = xw1[(k0 + kc + kk + 1) * NH + tid];
      float w2 = xw1[(k0 + kc + kk + 2) * NH + tid];
      float w3 = xw1[(k0 + kc + kk + 3) * NH + tid];
#pragma unroll
      for (int r = 0; r < 16; ++r) {
        float4 a = *(const float4*)&as[r][kk];
        acc[r] += a.x * w0 + a.y * w1 + a.z * w2 + a.w * w3;
      }
    }
    __syncthreads();
  }
  for (int r = 0; r < 16; ++r)
    atomicAdd(&hpre[(i0 + r) * NH + tid], acc[r]);
}

// ---------------------------------------------------------------------------
// k_qkv: h = relu(hpre); Qh/Kh/Vh = h @ Wq/Wk/Wv + bias. 16 rows/block, 128 thr.
// ---------------------------------------------------------------------------
__global__ void k_qkv(const float* __restrict__ hpre,
                      const float* __restrict__ Wq, const float* __restrict__ bq,
                      const float* __restrict__ Wk, const float* __restrict__ bk,
                      const float* __restrict__ Wv, const float* __restrict__ bv,
                      float* __restrict__ Qh, float* __restrict__ Kh,
                      float* __restrict__ Vh) {
  __shared__ float hs[16][NH];
  int i0 = blockIdx.x * 16;
  int tid = threadIdx.x;
  for (int l = tid; l < 16 * NH; l += 128) {
    int r = l >> 7, k = l & (NH - 1);
    hs[r][k] = fmaxf(hpre[(i0 + r) * NH + k], 0.f);
  }
  __syncthreads();
  float aq[16], ak[16], av[16];
#pragma unroll
  for (int r = 0; r < 16; ++r) { aq[r] = 0.f; ak[r] = 0.f; av[r] = 0.f; }
  for (int k = 0; k < NH; ++k) {
    float wq = Wq[k * NH + tid];
    float wk = Wk[k * NH + tid];
    float wv = Wv[k * NH + tid];
#pragma unroll
    for (int r = 0; r < 16; ++r) {
      float h = hs[r][k];
      aq[r] += h * wq; ak[r] += h * wk; av[r] += h * wv;
    }
  }
  for (int r = 0; r < 16; ++r) {
    Qh[(i0 + r) * NH + tid] = aq[r] + bq[tid];
    Kh[(i0 + r) * NH + tid] = ak[r] + bk[tid];
    Vh[(i0 + r) * NH + tid] = av[r] + bv[tid];
  }
}

// ---------------------------------------------------------------------------
// k_attn: flash-style fused  S = adj .* (Qh Kh^T); att = rowsoftmax(S);
//         Xt = relu(att @ Vh).   (gcn_norm(softmax) == identity, skipped.)
// 16 rows/block (256 blocks), 256 threads: thread (r, t16) owns 8-float slices.
// ---------------------------------------------------------------------------
#define AT_JT 32
__global__ void k_attn(const float* __restrict__ Qh, const float* __restrict__ Kh,
                       const float* __restrict__ Vh, const float* __restrict__ adj,
                       float* __restrict__ Xt) {
  __shared__ float Ks[AT_JT * 132];
  __shared__ float Vs[AT_JT * 132];
  __shared__ float adjs[16][AT_JT];
  __shared__ float ps[16][AT_JT];
  int i0 = blockIdx.x * 16;
  int tid = threadIdx.x;
  int r = tid >> 4, t16 = tid & 15;
  int row = i0 + r;
  float q[8];
#pragma unroll
  for (int kk = 0; kk < 8; ++kk) q[kk] = Qh[row * NH + t16 * 8 + kk];
  float m = -3.0e38f, l = 0.f;
  float acc[8];
#pragma unroll
  for (int c = 0; c < 8; ++c) acc[c] = 0.f;

  for (int jt = 0; jt < N; jt += AT_JT) {
    for (int t = tid; t < AT_JT * NH; t += 256) {
      int j = t >> 7, k = t & (NH - 1);
      Ks[j * 132 + k] = Kh[(jt + j) * NH + k];
      Vs[j * 132 + k] = Vh[(jt + j) * NH + k];
    }
    for (int t = tid; t < 16 * AT_JT; t += 256) {
      int rr = t >> 5, j = t & (AT_JT - 1);
      adjs[rr][j] = adj[(i0 + rr) * N + jt + j];
    }
    __syncthreads();

    float s0 = 0.f, s1 = 0.f, tmax = -3.0e38f;
#pragma unroll 4
    for (int j = 0; j < AT_JT; ++j) {
      const float4 k0 = *(const float4*)&Ks[j * 132 + t16 * 8];
      const float4 k1 = *(const float4*)&Ks[j * 132 + t16 * 8 + 4];
      float p = q[0] * k0.x + q[1] * k0.y + q[2] * k0.z + q[3] * k0.w
              + q[4] * k1.x + q[5] * k1.y + q[6] * k1.z + q[7] * k1.w;
      p += __shfl_xor(p, 1);
      p += __shfl_xor(p, 2);
      p += __shfl_xor(p, 4);
      p += __shfl_xor(p, 8);                 // all 16 lanes of the row hold the dot
      float s = adjs[r][j] * p;
      if (j == t16) s0 = s;
      if (j == t16 + 16) s1 = s;
      tmax = fmaxf(tmax, s);
    }
    float m_new = fmaxf(m, tmax);
    float scale = expf(m - m_new);
    float p0 = expf(s0 - m_new);
    float p1 = expf(s1 - m_new);
    float psum = p0 + p1;
    psum += __shfl_xor(psum, 1);
    psum += __shfl_xor(psum, 2);
    psum += __shfl_xor(psum, 4);
    psum += __shfl_xor(psum, 8);
    l = l * scale + psum;
    m = m_new;
    ps[r][t16] = p0;
    ps[r][t16 + 16] = p1;
#pragma unroll
    for (int c = 0; c < 8; ++c) acc[c] *= scale;
    // ps written+read by the same wave (16 contiguous lanes per row): no barrier
#pragma unroll 8
    for (int j = 0; j < AT_JT; ++j) {
      float p = ps[r][j];
      const float4 v0 = *(const float4*)&Vs[j * 132 + t16 * 8];
      const float4 v1 = *(const float4*)&Vs[j * 132 + t16 * 8 + 4];
      acc[0] += p * v0.x; acc[1] += p * v0.y; acc[2] += p * v0.z; acc[3] += p * v0.w;
      acc[4] += p * v1.x; acc[5] += p * v1.y; acc[6] += p * v1.z; acc[7] += p * v1.w;
    }
    __syncthreads();
  }
  float inv = 1.f / l;
#pragma unroll
  for (int c = 0; c < 8; ++c) {
    float v = acc[c] * inv;
    Xt[row * NH + t16 * 8 + c] = v > 0.f ? v : 0.f;
  }
}

// ---------------------------------------------------------------------------
// k_xtw2: xtw2 = Xt @ W2  ([N,128]@[128,16])
// ---------------------------------------------------------------------------
__global__ void k_xtw2(const float* __restrict__ Xt, const float* __restrict__ W2,
                       float* __restrict__ xtw2) {
  int i = blockIdx.x * 16 + (threadIdx.x >> 4);
  int c = threadIdx.x & 15;
  float acc = 0.f;
  for (int k = 0; k < NH; ++k) acc += Xt[i * NH + k] * W2[k * NC + c];
  xtw2[i * NC + c] = acc;
}

// ---------------------------------------------------------------------------
// k_z: z = adj @ xtw2 + b2; out = rowsoftmax(z).  16 rows/block, 256 threads.
// ---------------------------------------------------------------------------
__global__ void k_z(const float* __restrict__ adj, const float* __restrict__ xtw2,
                    const float* __restrict__ b2, float* __restrict__ out) {
  __shared__ float adjs[16][65];
  __shared__ float xws[64][17];
  int i0 = blockIdx.x * 16;
  int tid = threadIdx.x;
  int r = tid >> 4, c = tid & 15;
  float acc = 0.f;
  for (int j0 = 0; j0 < N; j0 += 64) {
    for (int t = tid; t < 1024; t += 256) {
      int rr = t >> 6, jj = t & 63;
      adjs[rr][jj] = adj[(i0 + rr) * N + j0 + jj];
      int j2 = t >> 4, c2 = t & 15;
      xws[j2][c2] = xtw2[(j0 + j2) * NC + c2];
    }
    __syncthreads();
#pragma unroll 16
    for (int jj = 0; jj < 64; ++jj) acc += adjs[r][jj] * xws[jj][c];
    __syncthreads();
  }
  acc += b2[c];
  float mv = acc;
  mv = fmaxf(mv, __shfl_xor(mv, 1));
  mv = fmaxf(mv, __shfl_xor(mv, 2));
  mv = fmaxf(mv, __shfl_xor(mv, 4));
  mv = fmaxf(mv, __shfl_xor(mv, 8));
  float e = expf(acc - mv);
  float s = e;
  s += __shfl_xor(s, 1);
  s += __shfl_xor(s, 2);
  s += __shfl_xor(s, 4);
  s += __shfl_xor(s, 8);
  out[i0 * NC + tid] = e / s;
}

// ---------------------------------------------------------------------------
extern "C" void kernel_launch(void* const* d_in, const int* in_sizes, int n_in,
                              void* d_out, int out_size, void* d_ws, size_t ws_size,
                              hipStream_t stream) {
  const float* A0  = (const float*)d_in[0];
  const float* A1  = (const float*)d_in[1];
  const float* A2  = (const float*)d_in[2];
  const float* x   = (const float*)d_in[3];
  const float* Wa1 = (const float*)d_in[4];  const float* ba1 = (const float*)d_in[5];
  const float* Wa2 = (const float*)d_in[6];  const float* ba2 = (const float*)d_in[7];
  const float* Wa3 = (const float*)d_in[8];  const float* ba3 = (const float*)d_in[9];
  const float* Wagg = (const float*)d_in[10]; const float* bagg = (const float*)d_in[11];
  const float* W1  = (const float*)d_in[12]; const float* b1  = (const float*)d_in[13];
  const float* Wq  = (const float*)d_in[14]; const float* bq  = (const float*)d_in[15];
  const float* Wk  = (const float*)d_in[16]; const float* bk  = (const float*)d_in[17];
  const float* Wv  = (const float*)d_in[18]; const float* bv  = (const float*)d_in[19];
  const float* W2  = (const float*)d_in[20]; const float* b2  = (const float*)d_in[21];

  float* out0 = (float*)d_out;            // [N,16] class softmax
  float* nz   = out0 + N * NC;            // [N,3] mixing weights (output 1)

  float* ws   = (float*)d_ws;             // ~80.1 MB of f32 scratch
  float* adj  = ws;                       // N*N
  float* Wc   = adj + (size_t)N * N;      // 3*N*3 as [j][k][c]
  float* bz   = Wc + 3 * N * 3;           // 3 (padded 16)
  float* xw1  = bz + 16;                  // N*NH
  float* hpre = xw1 + N * NH;             // N*NH
  float* Qh   = hpre + N * NH;            // N*NH
  float* Kh   = Qh + N * NH;              // N*NH
  float* Vh   = Kh + N * NH;              // N*NH
  float* Xt   = Vh + N * NH;              // N*NH
  float* xtw2 = Xt + N * NH;              // N*NC

  hipLaunchKernelGGL(k_wc, dim3(48), dim3(256), 0, stream,
                     Wa1, Wa2, Wa3, Wagg, ba1, ba2, ba3, bagg, Wc, bz);
  hipLaunchKernelGGL(k_z4nz, dim3(N / 16), dim3(256), 0, stream,
                     A0, A1, A2, Wc, bz, nz);
  hipLaunchKernelGGL(k_adj, dim3(N * N / 4 / 256), dim3(256), 0, stream,
                     A0, A1, A2, nz, adj);
  hipLaunchKernelGGL(k_xw1, dim3(N / 16), dim3(128), 0, stream, x, W1, xw1);
  hipLaunchKernelGGL(k_hinit, dim3(N * NH / 256), dim3(256), 0, stream, b1, hpre);
  hipLaunchKernelGGL(k_h, dim3(N / 16, 8), dim3(128), 0, stream, adj, xw1, hpre);
  hipLaunchKernelGGL(k_qkv, dim3(N / 16), dim3(128), 0, stream,
                     hpre, Wq, bq, Wk, bk, Wv, bv, Qh, Kh, Vh);
  hipLaunchKernelGGL(k_attn, dim3(N / 16), dim3(256), 0, stream, Qh, Kh, Vh, adj, Xt);
  hipLaunchKernelGGL(k_xtw2, dim3(N / 16), dim3(256), 0, stream, Xt, W2, xtw2);
  hipLaunchKernelGGL(k_z, dim3(N / 16), dim3(256), 0, stream, adj, xtw2, b2, out0);
}

// Round 2
// 638.506 us; speedup vs baseline: 3.3867x; 3.3867x over previous
//
#include <hip/hip_runtime.h>
#include <math.h>

#define N 4096
#define NF 512
#define NH 128
#define NC 16

// ---------------------------------------------------------------------------
// k_wc: Wc_k[j,c] = sum_t Wa_k[j,t] * Wagg[k*64+t, c]   (3*N*3 values)
// ---------------------------------------------------------------------------
__global__ void k_wc(const float* __restrict__ Wa1, const float* __restrict__ Wa2,
                     const float* __restrict__ Wa3, const float* __restrict__ Wagg,
                     const float* __restrict__ ba1, const float* __restrict__ ba2,
                     const float* __restrict__ ba3, const float* __restrict__ bagg,
                     float* __restrict__ Wc, float* __restrict__ bz) {
  int idx = blockIdx.x * 256 + threadIdx.x;
  if (idx < 3 * N) {
    int k = idx >> 12;
    int j = idx & (N - 1);
    const float* Wa = (k == 0) ? Wa1 : (k == 1) ? Wa2 : Wa3;
    float a0 = 0.f, a1 = 0.f, a2 = 0.f;
    for (int t = 0; t < 64; ++t) {
      float w = Wa[j * 64 + t];
      const float* wg = Wagg + (k * 64 + t) * 3;
      a0 += w * wg[0]; a1 += w * wg[1]; a2 += w * wg[2];
    }
    float* o = Wc + j * 9 + k * 3;
    o[0] = a0; o[1] = a1; o[2] = a2;
  }
  if (blockIdx.x == 0 && threadIdx.x < 3) {
    int c = threadIdx.x;
    float acc = bagg[c];
    for (int t = 0; t < 64; ++t) {
      acc += ba1[t] * Wagg[t * 3 + c]
           + ba2[t] * Wagg[(64 + t) * 3 + c]
           + ba3[t] * Wagg[(128 + t) * 3 + c];
    }
    bz[c] = acc;
  }
}

// ---------------------------------------------------------------------------
// k_z4nz: z4 + row softmax(3) -> nz
// ---------------------------------------------------------------------------
__global__ void k_z4nz(const float* __restrict__ A0, const float* __restrict__ A1,
                       const float* __restrict__ A2, const float* __restrict__ Wc,
                       const float* __restrict__ bz, float* __restrict__ nz) {
  __shared__ float red[16][3][4];
  int i0 = blockIdx.x * 16;
  int tid = threadIdx.x;
  float acc[16][3];
#pragma unroll
  for (int r = 0; r < 16; ++r) { acc[r][0] = 0.f; acc[r][1] = 0.f; acc[r][2] = 0.f; }
  for (int j = tid; j < N; j += 256) {
    const float* w = Wc + j * 9;
    float w0 = w[0], w1 = w[1], w2 = w[2], w3 = w[3], w4 = w[4];
    float w5 = w[5], w6 = w[6], w7 = w[7], w8 = w[8];
#pragma unroll
    for (int r = 0; r < 16; ++r) {
      float a0 = A0[(i0 + r) * N + j];
      float a1 = A1[(i0 + r) * N + j];
      float a2 = A2[(i0 + r) * N + j];
      acc[r][0] += a0 * w0 + a1 * w3 + a2 * w6;
      acc[r][1] += a0 * w1 + a1 * w4 + a2 * w7;
      acc[r][2] += a0 * w2 + a1 * w5 + a2 * w8;
    }
  }
  int lane = tid & 63, wv = tid >> 6;
#pragma unroll
  for (int r = 0; r < 16; ++r) {
#pragma unroll
    for (int c = 0; c < 3; ++c) {
      float v = acc[r][c];
      for (int off = 32; off > 0; off >>= 1) v += __shfl_down(v, off);
      if (lane == 0) red[r][c][wv] = v;
    }
  }
  __syncthreads();
  if (tid < 16) {
    float z0 = red[tid][0][0] + red[tid][0][1] + red[tid][0][2] + red[tid][0][3] + bz[0];
    float z1 = red[tid][1][0] + red[tid][1][1] + red[tid][1][2] + red[tid][1][3] + bz[1];
    float z2 = red[tid][2][0] + red[tid][2][1] + red[tid][2][2] + red[tid][2][3] + bz[2];
    float m = fmaxf(z0, fmaxf(z1, z2));
    float e0 = expf(z0 - m), e1 = expf(z1 - m), e2 = expf(z2 - m);
    float s = e0 + e1 + e2;
    float* o = nz + (i0 + tid) * 3;
    o[0] = e0 / s; o[1] = e1 / s; o[2] = e2 / s;
  }
}

// ---------------------------------------------------------------------------
// k_adj: adj[i,j] = A0*nz[j,0] + A1*nz[j,1] + A2*nz[j,2]  (column-broadcast)
// ---------------------------------------------------------------------------
__global__ void k_adj(const float* __restrict__ A0, const float* __restrict__ A1,
                      const float* __restrict__ A2, const float* __restrict__ nz,
                      float* __restrict__ adj) {
  int idx = blockIdx.x * 256 + threadIdx.x;
  int i = idx >> 10;
  int j4 = (idx & 1023) << 2;
  int base = i * N + j4;
  const float4 a0 = *(const float4*)&A0[base];
  const float4 a1 = *(const float4*)&A1[base];
  const float4 a2 = *(const float4*)&A2[base];
  const float4 n0 = *(const float4*)&nz[j4 * 3];
  const float4 n1 = *(const float4*)&nz[j4 * 3 + 4];
  const float4 n2 = *(const float4*)&nz[j4 * 3 + 8];
  float4 o;
  o.x = a0.x * n0.x + a1.x * n0.y + a2.x * n0.z;
  o.y = a0.y * n0.w + a1.y * n1.x + a2.y * n1.y;
  o.z = a0.z * n1.z + a1.z * n1.w + a2.z * n2.x;
  o.w = a0.w * n2.y + a1.w * n2.z + a2.w * n2.w;
  *(float4*)&adj[base] = o;
}

// ---------------------------------------------------------------------------
// k_xw1: xw1 = x @ W1
// ---------------------------------------------------------------------------
__global__ void k_xw1(const float* __restrict__ x, const float* __restrict__ W1,
                      float* __restrict__ xw1) {
  __shared__ float xs[16][NF];
  int i0 = blockIdx.x * 16;
  int tid = threadIdx.x;
  for (int l = tid; l < 16 * NF; l += 128) {
    int r = l >> 9, k = l & (NF - 1);
    xs[r][k] = x[(i0 + r) * NF + k];
  }
  __syncthreads();
  float acc[16];
#pragma unroll
  for (int r = 0; r < 16; ++r) acc[r] = 0.f;
  for (int k = 0; k < NF; ++k) {
    float w = W1[k * NH + tid];
#pragma unroll
    for (int r = 0; r < 16; ++r) acc[r] += xs[r][k] * w;
  }
  for (int r = 0; r < 16; ++r) xw1[(i0 + r) * NH + tid] = acc[r];
}

__global__ void k_hinit(const float* __restrict__ b1, float* __restrict__ hpre) {
  int idx = blockIdx.x * 256 + threadIdx.x;
  if (idx < N * NH) hpre[idx] = b1[idx & (NH - 1)];
}

// ---------------------------------------------------------------------------
// k_h: hpre += adj @ xw1  (split-K, atomics)
// ---------------------------------------------------------------------------
__global__ void k_h(const float* __restrict__ adj, const float* __restrict__ xw1,
                    float* __restrict__ hpre) {
  __shared__ float as[16][256];
  int i0 = blockIdx.x * 16;
  int k0 = blockIdx.y * 512;
  int tid = threadIdx.x;
  float acc[16];
#pragma unroll
  for (int r = 0; r < 16; ++r) acc[r] = 0.f;
  for (int kc = 0; kc < 512; kc += 256) {
    for (int l = tid; l < 16 * 256; l += 128) {
      int r = l >> 8, kk = l & 255;
      as[r][kk] = adj[(i0 + r) * N + k0 + kc + kk];
    }
    __syncthreads();
    for (int kk = 0; kk < 256; kk += 4) {
      float w0 = xw1[(k0 + kc + kk + 0) * NH + tid];
      float w1 = xw1[(k0 + kc + kk + 1) * NH + tid];
      float w2 = xw1[(k0 + kc + kk + 2) * NH + tid];
      float w3 = xw1[(k0 + kc + kk + 3) * NH + tid];
#pragma unroll
      for (int r = 0; r < 16; ++r) {
        float4 a = *(const float4*)&as[r][kk];
        acc[r] += a.x * w0 + a.y * w1 + a.z * w2 + a.w * w3;
      }
    }
    __syncthreads();
  }
  for (int r = 0; r < 16; ++r)
    atomicAdd(&hpre[(i0 + r) * NH + tid], acc[r]);
}

// ---------------------------------------------------------------------------
// k_qkv: h = relu(hpre); QhT/KhT (transposed, d-major) and Vh (row-major)
// ---------------------------------------------------------------------------
__global__ void k_qkv(const float* __restrict__ hpre,
                      const float* __restrict__ Wq, const float* __restrict__ bq,
                      const float* __restrict__ Wk, const float* __restrict__ bk,
                      const float* __restrict__ Wv, const float* __restrict__ bv,
                      float* __restrict__ QhT, float* __restrict__ KhT,
                      float* __restrict__ Vh) {
  __shared__ float hs[16][NH];
  int i0 = blockIdx.x * 16;
  int tid = threadIdx.x;
  for (int l = tid; l < 16 * NH; l += 128) {
    int r = l >> 7, k = l & (NH - 1);
    hs[r][k] = fmaxf(hpre[(i0 + r) * NH + k], 0.f);
  }
  __syncthreads();
  float aq[16], ak[16], av[16];
#pragma unroll
  for (int r = 0; r < 16; ++r) { aq[r] = 0.f; ak[r] = 0.f; av[r] = 0.f; }
  for (int k = 0; k < NH; ++k) {
    float wq = Wq[k * NH + tid];
    float wk = Wk[k * NH + tid];
    float wv = Wv[k * NH + tid];
#pragma unroll
    for (int r = 0; r < 16; ++r) {
      float h = hs[r][k];
      aq[r] += h * wq; ak[r] += h * wk; av[r] += h * wv;
    }
  }
  float bqv = bq[tid], bkv = bk[tid], bvv = bv[tid];
#pragma unroll
  for (int r = 0; r < 16; r += 4) {
    float4 q = {aq[r] + bqv, aq[r + 1] + bqv, aq[r + 2] + bqv, aq[r + 3] + bqv};
    float4 k4 = {ak[r] + bkv, ak[r + 1] + bkv, ak[r + 2] + bkv, ak[r + 3] + bkv};
    *(float4*)&QhT[tid * N + i0 + r] = q;
    *(float4*)&KhT[tid * N + i0 + r] = k4;
  }
  for (int r = 0; r < 16; ++r) Vh[(i0 + r) * NH + tid] = av[r] + bvv;
}

// ---------------------------------------------------------------------------
// k_attn: partial flash attention over a 1024-column chunk.
//   S = adj .* (Q K^T); online softmax; Xp = P@V (unnormalized), (m,l) saved.
// Grid (64, 4): blockIdx.x = 64-row block, blockIdx.y = column chunk.
// 512 threads: ty = tid>>5 (0..15) -> rows 4ty..4ty+3; tx = tid&31.
// QK per-thread: 4 rows x 2 cols.  PV per-thread: 4 rows x 4 cols.
// LDS 96 KB: Qs[128][64] d-major, KPs[128][64] d-major (reused as Ps[64][64]
// row-major after QK), Vs[64][128] row-major.
// ---------------------------------------------------------------------------
__global__ __launch_bounds__(512) void k_attn(
    const float* __restrict__ QhT, const float* __restrict__ KhT,
    const float* __restrict__ Vh, const float* __restrict__ adj,
    float* __restrict__ xp0, float* __restrict__ xp1,
    float* __restrict__ xp2, float* __restrict__ xp3,
    float* __restrict__ ml) {
  __shared__ float Qs[128 * 64];
  __shared__ float KPs[128 * 64];
  __shared__ float Vs[64 * 128];
  int i0 = blockIdx.x * 64;
  int cid = blockIdx.y;
  int c0 = cid * 1024;
  int tid = threadIdx.x;
  int ty = tid >> 5, tx = tid & 31;
  float* xp = (cid == 0) ? xp0 : (cid == 1) ? xp1 : (cid == 2) ? xp2 : xp3;

  // stage Q (d-major) once: Qs[d][r] = QhT[d][i0+r]
  for (int q = tid; q < 2048; q += 512) {
    int d = q >> 4, c4 = (q & 15) << 2;
    *(float4*)&Qs[d * 64 + c4] = *(const float4*)&QhT[d * N + i0 + c4];
  }

  float m[4], l[4], X[4][4];
#pragma unroll
  for (int i = 0; i < 4; ++i) {
    m[i] = -3.0e38f; l[i] = 0.f;
#pragma unroll
    for (int c = 0; c < 4; ++c) X[i][c] = 0.f;
  }

  for (int jt = 0; jt < 16; ++jt) {
    int j0g = c0 + jt * 64;
    __syncthreads();                 // prior PV done (and Qs staged, iter 0)
    // stage K (d-major) and V (row-major)
    for (int q = tid; q < 2048; q += 512) {
      int d = q >> 4, c4 = (q & 15) << 2;
      *(float4*)&KPs[d * 64 + c4] = *(const float4*)&KhT[d * N + j0g + c4];
    }
    for (int q = tid; q < 2048; q += 512) {
      int j = q >> 5, d4 = (q & 31) << 2;
      *(float4*)&Vs[j * 128 + d4] = *(const float4*)&Vh[(j0g + j) * NH + d4];
    }
    // adj mask into registers (issued early; consumed after QK)
    float2 adjv[4];
#pragma unroll
    for (int i = 0; i < 4; ++i)
      adjv[i] = *(const float2*)&adj[(i0 + 4 * ty + i) * N + j0g + 2 * tx];
    __syncthreads();

    // QK^T: s[4 rows][2 cols]
    float s00 = 0.f, s01 = 0.f, s10 = 0.f, s11 = 0.f;
    float s20 = 0.f, s21 = 0.f, s30 = 0.f, s31 = 0.f;
#pragma unroll 4
    for (int k = 0; k < 128; ++k) {
      const float4 qv = *(const float4*)&Qs[k * 64 + 4 * ty];
      const float2 kv = *(const float2*)&KPs[k * 64 + 2 * tx];
      s00 += qv.x * kv.x; s01 += qv.x * kv.y;
      s10 += qv.y * kv.x; s11 += qv.y * kv.y;
      s20 += qv.z * kv.x; s21 += qv.z * kv.y;
      s30 += qv.w * kv.x; s31 += qv.w * kv.y;
    }
    float sm[4][2] = {{s00, s01}, {s10, s11}, {s20, s21}, {s30, s31}};
    float p[4][2], scale[4];
#pragma unroll
    for (int i = 0; i < 4; ++i) {
      float a0 = sm[i][0] * adjv[i].x;
      float a1 = sm[i][1] * adjv[i].y;
      float t = fmaxf(a0, a1);
      t = fmaxf(t, __shfl_xor(t, 1));
      t = fmaxf(t, __shfl_xor(t, 2));
      t = fmaxf(t, __shfl_xor(t, 4));
      t = fmaxf(t, __shfl_xor(t, 8));
      t = fmaxf(t, __shfl_xor(t, 16));
      float mn = fmaxf(m[i], t);
      float sc = __expf(m[i] - mn);
      float p0 = __expf(a0 - mn);
      float p1 = __expf(a1 - mn);
      float ps = p0 + p1;
      ps += __shfl_xor(ps, 1);
      ps += __shfl_xor(ps, 2);
      ps += __shfl_xor(ps, 4);
      ps += __shfl_xor(ps, 8);
      ps += __shfl_xor(ps, 16);
      l[i] = l[i] * sc + ps;
      m[i] = mn;
      scale[i] = sc;
      p[i][0] = p0; p[i][1] = p1;
#pragma unroll
      for (int c = 0; c < 4; ++c) X[i][c] *= sc;
    }
    __syncthreads();                 // all QK reads of KPs complete
    // write P (row-major) into KPs region
#pragma unroll
    for (int i = 0; i < 4; ++i) {
      float2 pv = {p[i][0], p[i][1]};
      *(float2*)&KPs[(4 * ty + i) * 64 + 2 * tx] = pv;
    }
    __syncthreads();

    // PV: X[4 rows][4 cols] += P[rows][j] * V[j][4tx..]
#pragma unroll 2
    for (int j0 = 0; j0 < 64; j0 += 4) {
      float4 pr[4];
#pragma unroll
      for (int i = 0; i < 4; ++i)
        pr[i] = *(const float4*)&KPs[(4 * ty + i) * 64 + j0];
#pragma unroll
      for (int jj = 0; jj < 4; ++jj) {
        const float4 vv = *(const float4*)&Vs[(j0 + jj) * 128 + 4 * tx];
#pragma unroll
        for (int i = 0; i < 4; ++i) {
          float pj = ((const float*)&pr[i])[jj];
          X[i][0] += pj * vv.x; X[i][1] += pj * vv.y;
          X[i][2] += pj * vv.z; X[i][3] += pj * vv.w;
        }
      }
    }
  }

#pragma unroll
  for (int i = 0; i < 4; ++i) {
    float4 o = {X[i][0], X[i][1], X[i][2], X[i][3]};
    *(float4*)&xp[(i0 + 4 * ty + i) * NH + 4 * tx] = o;
    if (tx == 0) {
      ml[(cid * N + i0 + 4 * ty + i) * 2 + 0] = m[i];
      ml[(cid * N + i0 + 4 * ty + i) * 2 + 1] = l[i];
    }
  }
}

// ---------------------------------------------------------------------------
// k_comb: merge 4 chunk-partials, normalize, relu -> Xt
// ---------------------------------------------------------------------------
__global__ void k_comb(const float* __restrict__ xp0, const float* __restrict__ xp1,
                       const float* __restrict__ xp2, const float* __restrict__ xp3,
                       const float* __restrict__ ml, float* __restrict__ Xt) {
  int idx = blockIdx.x * 256 + threadIdx.x;   // 512 blocks
  int r = idx >> 5, d4 = (idx & 31) << 2;
  float m0 = ml[(0 * N + r) * 2], l0 = ml[(0 * N + r) * 2 + 1];
  float m1 = ml[(1 * N + r) * 2], l1 = ml[(1 * N + r) * 2 + 1];
  float m2 = ml[(2 * N + r) * 2], l2 = ml[(2 * N + r) * 2 + 1];
  float m3 = ml[(3 * N + r) * 2], l3 = ml[(3 * N + r) * 2 + 1];
  float ms = fmaxf(fmaxf(m0, m1), fmaxf(m2, m3));
  float e0 = __expf(m0 - ms), e1 = __expf(m1 - ms);
  float e2 = __expf(m2 - ms), e3 = __expf(m3 - ms);
  float inv = 1.f / (e0 * l0 + e1 * l1 + e2 * l2 + e3 * l3);
  const float4 a0 = *(const float4*)&xp0[r * NH + d4];
  const float4 a1 = *(const float4*)&xp1[r * NH + d4];
  const float4 a2 = *(const float4*)&xp2[r * NH + d4];
  const float4 a3 = *(const float4*)&xp3[r * NH + d4];
  float4 o;
  o.x = fmaxf((a0.x * e0 + a1.x * e1 + a2.x * e2 + a3.x * e3) * inv, 0.f);
  o.y = fmaxf((a0.y * e0 + a1.y * e1 + a2.y * e2 + a3.y * e3) * inv, 0.f);
  o.z = fmaxf((a0.z * e0 + a1.z * e1 + a2.z * e2 + a3.z * e3) * inv, 0.f);
  o.w = fmaxf((a0.w * e0 + a1.w * e1 + a2.w * e2 + a3.w * e3) * inv, 0.f);
  *(float4*)&Xt[r * NH + d4] = o;
}

// ---------------------------------------------------------------------------
// k_xtw2: xtw2 = Xt @ W2
// ---------------------------------------------------------------------------
__global__ void k_xtw2(const float* __restrict__ Xt, const float* __restrict__ W2,
                       float* __restrict__ xtw2) {
  int i = blockIdx.x * 16 + (threadIdx.x >> 4);
  int c = threadIdx.x & 15;
  float acc = 0.f;
  for (int k = 0; k < NH; ++k) acc += Xt[i * NH + k] * W2[k * NC + c];
  xtw2[i * NC + c] = acc;
}

// ---------------------------------------------------------------------------
// k_z: z = adj @ xtw2 + b2; out = rowsoftmax(z)
// ---------------------------------------------------------------------------
__global__ void k_z(const float* __restrict__ adj, const float* __restrict__ xtw2,
                    const float* __restrict__ b2, float* __restrict__ out) {
  __shared__ float adjs[16][65];
  __shared__ float xws[64][17];
  int i0 = blockIdx.x * 16;
  int tid = threadIdx.x;
  int r = tid >> 4, c = tid & 15;
  float acc = 0.f;
  for (int j0 = 0; j0 < N; j0 += 64) {
    for (int t = tid; t < 1024; t += 256) {
      int rr = t >> 6, jj = t & 63;
      adjs[rr][jj] = adj[(i0 + rr) * N + j0 + jj];
      int j2 = t >> 4, c2 = t & 15;
      xws[j2][c2] = xtw2[(j0 + j2) * NC + c2];
    }
    __syncthreads();
#pragma unroll 16
    for (int jj = 0; jj < 64; ++jj) acc += adjs[r][jj] * xws[jj][c];
    __syncthreads();
  }
  acc += b2[c];
  float mv = acc;
  mv = fmaxf(mv, __shfl_xor(mv, 1));
  mv = fmaxf(mv, __shfl_xor(mv, 2));
  mv = fmaxf(mv, __shfl_xor(mv, 4));
  mv = fmaxf(mv, __shfl_xor(mv, 8));
  float e = expf(acc - mv);
  float s = e;
  s += __shfl_xor(s, 1);
  s += __shfl_xor(s, 2);
  s += __shfl_xor(s, 4);
  s += __shfl_xor(s, 8);
  out[i0 * NC + tid] = e / s;
}

// ---------------------------------------------------------------------------
extern "C" void kernel_launch(void* const* d_in, const int* in_sizes, int n_in,
                              void* d_out, int out_size, void* d_ws, size_t ws_size,
                              hipStream_t stream) {
  const float* A0  = (const float*)d_in[0];
  const float* A1  = (const float*)d_in[1];
  const float* A2  = (const float*)d_in[2];
  const float* x   = (const float*)d_in[3];
  const float* Wa1 = (const float*)d_in[4];  const float* ba1 = (const float*)d_in[5];
  const float* Wa2 = (const float*)d_in[6];  const float* ba2 = (const float*)d_in[7];
  const float* Wa3 = (const float*)d_in[8];  const float* ba3 = (const float*)d_in[9];
  const float* Wagg = (const float*)d_in[10]; const float* bagg = (const float*)d_in[11];
  const float* W1  = (const float*)d_in[12]; const float* b1  = (const float*)d_in[13];
  const float* Wq  = (const float*)d_in[14]; const float* bq  = (const float*)d_in[15];
  const float* Wk  = (const float*)d_in[16]; const float* bk  = (const float*)d_in[17];
  const float* Wv  = (const float*)d_in[18]; const float* bv  = (const float*)d_in[19];
  const float* W2  = (const float*)d_in[20]; const float* b2  = (const float*)d_in[21];

  float* out0 = (float*)d_out;            // [N,16] class softmax
  float* nz   = out0 + N * NC;            // [N,3] mixing weights (output 1)

  float* ws   = (float*)d_ws;
  float* adj  = ws;                       // N*N
  float* Wc   = adj + (size_t)N * N;      // 3*N*3
  float* bz   = Wc + 3 * N * 3;           // 16
  float* xw1  = bz + 16;                  // N*NH   (later: Xp chunk 0)
  float* hpre = xw1 + N * NH;             // N*NH   (later: Xp chunk 1)
  float* QhT  = hpre + N * NH;            // N*NH  transposed [128][4096]
  float* KhT  = QhT + N * NH;             // N*NH  transposed [128][4096]
  float* Vh   = KhT + N * NH;             // N*NH
  float* Xt   = Vh + N * NH;              // N*NH   (also Xp chunk 3)
  float* xtw2 = Xt + N * NH;              // N*NC
  float* Xp2  = xtw2 + N * NC;            // N*NH   (Xp chunk 2)
  float* ml   = Xp2 + N * NH;             // 4*N*2

  hipLaunchKernelGGL(k_wc, dim3(48), dim3(256), 0, stream,
                     Wa1, Wa2, Wa3, Wagg, ba1, ba2, ba3, bagg, Wc, bz);
  hipLaunchKernelGGL(k_z4nz, dim3(N / 16), dim3(256), 0, stream,
                     A0, A1, A2, Wc, bz, nz);
  hipLaunchKernelGGL(k_adj, dim3(N * N / 4 / 256), dim3(256), 0, stream,
                     A0, A1, A2, nz, adj);
  hipLaunchKernelGGL(k_xw1, dim3(N / 16), dim3(128), 0, stream, x, W1, xw1);
  hipLaunchKernelGGL(k_hinit, dim3(N * NH / 256), dim3(256), 0, stream, b1, hpre);
  hipLaunchKernelGGL(k_h, dim3(N / 16, 8), dim3(128), 0, stream, adj, xw1, hpre);
  hipLaunchKernelGGL(k_qkv, dim3(N / 16), dim3(128), 0, stream,
                     hpre, Wq, bq, Wk, bk, Wv, bv, QhT, KhT, Vh);
  hipLaunchKernelGGL(k_attn, dim3(N / 64, 4), dim3(512), 0, stream,
                     QhT, KhT, Vh, adj, xw1, hpre, Xp2, Xt, ml);
  hipLaunchKernelGGL(k_comb, dim3(N * 32 / 256), dim3(256), 0, stream,
                     xw1, hpre, Xp2, Xt, ml, Xt);
  hipLaunchKernelGGL(k_xtw2, dim3(N / 16), dim3(256), 0, stream, Xt, W2, xtw2);
  hipLaunchKernelGGL(k_z, dim3(N / 16), dim3(256), 0, stream, adj, xtw2, b2, out0);
}

// Round 3
// 636.437 us; speedup vs baseline: 3.3977x; 1.0032x over previous
//
#include <hip/hip_runtime.h>
#include <math.h>

#define N 4096
#define NF 512
#define NH 128
#define NC 16
#define CSPLIT 8

// ---------------------------------------------------------------------------
// k_wc: Wc_k[j,c] = sum_t Wa_k[j,t] * Wagg[k*64+t, c]   (3*N*3 values)
// ---------------------------------------------------------------------------
__global__ void k_wc(const float* __restrict__ Wa1, const float* __restrict__ Wa2,
                     const float* __restrict__ Wa3, const float* __restrict__ Wagg,
                     const float* __restrict__ ba1, const float* __restrict__ ba2,
                     const float* __restrict__ ba3, const float* __restrict__ bagg,
                     float* __restrict__ Wc, float* __restrict__ bz) {
  int idx = blockIdx.x * 256 + threadIdx.x;
  if (idx < 3 * N) {
    int k = idx >> 12;
    int j = idx & (N - 1);
    const float* Wa = (k == 0) ? Wa1 : (k == 1) ? Wa2 : Wa3;
    float a0 = 0.f, a1 = 0.f, a2 = 0.f;
    for (int t = 0; t < 64; ++t) {
      float w = Wa[j * 64 + t];
      const float* wg = Wagg + (k * 64 + t) * 3;
      a0 += w * wg[0]; a1 += w * wg[1]; a2 += w * wg[2];
    }
    float* o = Wc + j * 9 + k * 3;
    o[0] = a0; o[1] = a1; o[2] = a2;
  }
  if (blockIdx.x == 0 && threadIdx.x < 3) {
    int c = threadIdx.x;
    float acc = bagg[c];
    for (int t = 0; t < 64; ++t) {
      acc += ba1[t] * Wagg[t * 3 + c]
           + ba2[t] * Wagg[(64 + t) * 3 + c]
           + ba3[t] * Wagg[(128 + t) * 3 + c];
    }
    bz[c] = acc;
  }
}

// ---------------------------------------------------------------------------
// k_z4nz: z4 + row softmax(3) -> nz  (float4 A loads; memory-bound)
// ---------------------------------------------------------------------------
__global__ void k_z4nz(const float* __restrict__ A0, const float* __restrict__ A1,
                       const float* __restrict__ A2, const float* __restrict__ Wc,
                       const float* __restrict__ bz, float* __restrict__ nz) {
  __shared__ float red[16][3][4];
  int i0 = blockIdx.x * 16;
  int tid = threadIdx.x;
  float acc[16][3];
#pragma unroll
  for (int r = 0; r < 16; ++r) { acc[r][0] = 0.f; acc[r][1] = 0.f; acc[r][2] = 0.f; }
  for (int j4 = tid * 4; j4 < N; j4 += 1024) {
    float w[36];
#pragma unroll
    for (int q = 0; q < 9; ++q) {
      const float4 v = *(const float4*)&Wc[j4 * 9 + q * 4];
      w[4 * q] = v.x; w[4 * q + 1] = v.y; w[4 * q + 2] = v.z; w[4 * q + 3] = v.w;
    }
#pragma unroll
    for (int r = 0; r < 16; ++r) {
      const float4 a0 = *(const float4*)&A0[(i0 + r) * N + j4];
      const float4 a1 = *(const float4*)&A1[(i0 + r) * N + j4];
      const float4 a2 = *(const float4*)&A2[(i0 + r) * N + j4];
#pragma unroll
      for (int jj = 0; jj < 4; ++jj) {
        float x0 = ((const float*)&a0)[jj];
        float x1 = ((const float*)&a1)[jj];
        float x2 = ((const float*)&a2)[jj];
#pragma unroll
        for (int cc = 0; cc < 3; ++cc)
          acc[r][cc] += x0 * w[jj * 9 + cc] + x1 * w[jj * 9 + 3 + cc]
                      + x2 * w[jj * 9 + 6 + cc];
      }
    }
  }
  int lane = tid & 63, wv = tid >> 6;
#pragma unroll
  for (int r = 0; r < 16; ++r) {
#pragma unroll
    for (int c = 0; c < 3; ++c) {
      float v = acc[r][c];
      for (int off = 32; off > 0; off >>= 1) v += __shfl_down(v, off);
      if (lane == 0) red[r][c][wv] = v;
    }
  }
  __syncthreads();
  if (tid < 16) {
    float z0 = red[tid][0][0] + red[tid][0][1] + red[tid][0][2] + red[tid][0][3] + bz[0];
    float z1 = red[tid][1][0] + red[tid][1][1] + red[tid][1][2] + red[tid][1][3] + bz[1];
    float z2 = red[tid][2][0] + red[tid][2][1] + red[tid][2][2] + red[tid][2][3] + bz[2];
    float m = fmaxf(z0, fmaxf(z1, z2));
    float e0 = expf(z0 - m), e1 = expf(z1 - m), e2 = expf(z2 - m);
    float s = e0 + e1 + e2;
    float* o = nz + (i0 + tid) * 3;
    o[0] = e0 / s; o[1] = e1 / s; o[2] = e2 / s;
  }
}

// ---------------------------------------------------------------------------
// k_adj: adj[i,j] = A0*nz[j,0] + A1*nz[j,1] + A2*nz[j,2]  (column-broadcast)
// ---------------------------------------------------------------------------
__global__ void k_adj(const float* __restrict__ A0, const float* __restrict__ A1,
                      const float* __restrict__ A2, const float* __restrict__ nz,
                      float* __restrict__ adj) {
  int idx = blockIdx.x * 256 + threadIdx.x;
  int i = idx >> 10;
  int j4 = (idx & 1023) << 2;
  int base = i * N + j4;
  const float4 a0 = *(const float4*)&A0[base];
  const float4 a1 = *(const float4*)&A1[base];
  const float4 a2 = *(const float4*)&A2[base];
  const float4 n0 = *(const float4*)&nz[j4 * 3];
  const float4 n1 = *(const float4*)&nz[j4 * 3 + 4];
  const float4 n2 = *(const float4*)&nz[j4 * 3 + 8];
  float4 o;
  o.x = a0.x * n0.x + a1.x * n0.y + a2.x * n0.z;
  o.y = a0.y * n0.w + a1.y * n1.x + a2.y * n1.y;
  o.z = a0.z * n1.z + a1.z * n1.w + a2.z * n2.x;
  o.w = a0.w * n2.y + a1.w * n2.z + a2.w * n2.w;
  *(float4*)&adj[base] = o;
}

// ---------------------------------------------------------------------------
// k_xw1: xw1 = x @ W1
// ---------------------------------------------------------------------------
__global__ void k_xw1(const float* __restrict__ x, const float* __restrict__ W1,
                      float* __restrict__ xw1) {
  __shared__ float xs[16][NF];
  int i0 = blockIdx.x * 16;
  int tid = threadIdx.x;
  for (int l = tid; l < 16 * NF; l += 128) {
    int r = l >> 9, k = l & (NF - 1);
    xs[r][k] = x[(i0 + r) * NF + k];
  }
  __syncthreads();
  float acc[16];
#pragma unroll
  for (int r = 0; r < 16; ++r) acc[r] = 0.f;
  for (int k = 0; k < NF; ++k) {
    float w = W1[k * NH + tid];
#pragma unroll
    for (int r = 0; r < 16; ++r) acc[r] += xs[r][k] * w;
  }
  for (int r = 0; r < 16; ++r) xw1[(i0 + r) * NH + tid] = acc[r];
}

__global__ void k_hinit(const float* __restrict__ b1, float* __restrict__ hpre) {
  int idx = blockIdx.x * 256 + threadIdx.x;
  if (idx < N * NH) hpre[idx] = b1[idx & (NH - 1)];
}

// ---------------------------------------------------------------------------
// k_h: hpre += adj @ xw1.  Grid (32, 8) = 256 blocks, 256 threads.
// BM=128, BN=128(=NH), per-block K-range 512 (8 x BK=64), per-thread 8x8.
// adjT staged transposed [k][r] stride 132; xw1s [k][c] stride 132.
// ---------------------------------------------------------------------------
__global__ __launch_bounds__(256) void k_h(const float* __restrict__ adj,
                                           const float* __restrict__ xw1,
                                           float* __restrict__ hpre) {
  __shared__ float adjT[64 * 132];
  __shared__ float xw1s[64 * 132];
  int i0 = blockIdx.x * 128;
  int kbase = blockIdx.y * 512;
  int tid = threadIdx.x;
  int ty = tid >> 4, tx = tid & 15;        // rows 8ty..+7; cols 4tx, 64+4tx
  float acc[8][8];
#pragma unroll
  for (int i = 0; i < 8; ++i)
#pragma unroll
    for (int c = 0; c < 8; ++c) acc[i][c] = 0.f;

  int rs = tid >> 1, kh = (tid & 1) * 32;  // staging map for adjT
  for (int t = 0; t < 8; ++t) {
    int k0 = kbase + t * 64;
    __syncthreads();                       // prior compute done
#pragma unroll
    for (int q = 0; q < 8; ++q) {
      int k4 = kh + q * 4;
      const float4 v = *(const float4*)&adj[(i0 + rs) * N + k0 + k4];
      adjT[(k4 + 0) * 132 + rs] = v.x;
      adjT[(k4 + 1) * 132 + rs] = v.y;
      adjT[(k4 + 2) * 132 + rs] = v.z;
      adjT[(k4 + 3) * 132 + rs] = v.w;
    }
#pragma unroll
    for (int s = 0; s < 8; ++s) {
      int f4 = tid + 256 * s;
      int k = f4 >> 5, c4 = (f4 & 31) << 2;
      *(float4*)&xw1s[k * 132 + c4] = *(const float4*)&xw1[(k0 + k) * NH + c4];
    }
    __syncthreads();
#pragma unroll 4
    for (int k = 0; k < 64; ++k) {
      const float4 a0 = *(const float4*)&adjT[k * 132 + 8 * ty];
      const float4 a1 = *(const float4*)&adjT[k * 132 + 8 * ty + 4];
      const float4 w0 = *(const float4*)&xw1s[k * 132 + 4 * tx];
      const float4 w1 = *(const float4*)&xw1s[k * 132 + 64 + 4 * tx];
#pragma unroll
      for (int i = 0; i < 4; ++i) {
        float ai = ((const float*)&a0)[i];
        acc[i][0] += ai * w0.x; acc[i][1] += ai * w0.y;
        acc[i][2] += ai * w0.z; acc[i][3] += ai * w0.w;
        acc[i][4] += ai * w1.x; acc[i][5] += ai * w1.y;
        acc[i][6] += ai * w1.z; acc[i][7] += ai * w1.w;
        float bi = ((const float*)&a1)[i];
        acc[4 + i][0] += bi * w0.x; acc[4 + i][1] += bi * w0.y;
        acc[4 + i][2] += bi * w0.z; acc[4 + i][3] += bi * w0.w;
        acc[4 + i][4] += bi * w1.x; acc[4 + i][5] += bi * w1.y;
        acc[4 + i][6] += bi * w1.z; acc[4 + i][7] += bi * w1.w;
      }
    }
  }
#pragma unroll
  for (int i = 0; i < 8; ++i) {
    int row = i0 + 8 * ty + i;
#pragma unroll
    for (int c = 0; c < 4; ++c)
      atomicAdd(&hpre[row * NH + 4 * tx + c], acc[i][c]);
#pragma unroll
    for (int c = 0; c < 4; ++c)
      atomicAdd(&hpre[row * NH + 64 + 4 * tx + c], acc[i][4 + c]);
  }
}

// ---------------------------------------------------------------------------
// k_qkv: h = relu(hpre); QhT/KhT (transposed, d-major) and Vh (row-major)
// ---------------------------------------------------------------------------
__global__ void k_qkv(const float* __restrict__ hpre,
                      const float* __restrict__ Wq, const float* __restrict__ bq,
                      const float* __restrict__ Wk, const float* __restrict__ bk,
                      const float* __restrict__ Wv, const float* __restrict__ bv,
                      float* __restrict__ QhT, float* __restrict__ KhT,
                      float* __restrict__ Vh) {
  __shared__ float hs[16][NH];
  int i0 = blockIdx.x * 16;
  int tid = threadIdx.x;
  for (int l = tid; l < 16 * NH; l += 128) {
    int r = l >> 7, k = l & (NH - 1);
    hs[r][k] = fmaxf(hpre[(i0 + r) * NH + k], 0.f);
  }
  __syncthreads();
  float aq[16], ak[16], av[16];
#pragma unroll
  for (int r = 0; r < 16; ++r) { aq[r] = 0.f; ak[r] = 0.f; av[r] = 0.f; }
  for (int k = 0; k < NH; ++k) {
    float wq = Wq[k * NH + tid];
    float wk = Wk[k * NH + tid];
    float wv = Wv[k * NH + tid];
#pragma unroll
    for (int r = 0; r < 16; ++r) {
      float h = hs[r][k];
      aq[r] += h * wq; ak[r] += h * wk; av[r] += h * wv;
    }
  }
  float bqv = bq[tid], bkv = bk[tid], bvv = bv[tid];
#pragma unroll
  for (int r = 0; r < 16; r += 4) {
    float4 q = {aq[r] + bqv, aq[r + 1] + bqv, aq[r + 2] + bqv, aq[r + 3] + bqv};
    float4 k4 = {ak[r] + bkv, ak[r + 1] + bkv, ak[r + 2] + bkv, ak[r + 3] + bkv};
    *(float4*)&QhT[tid * N + i0 + r] = q;
    *(float4*)&KhT[tid * N + i0 + r] = k4;
  }
  for (int r = 0; r < 16; ++r) Vh[(i0 + r) * NH + tid] = av[r] + bvv;
}

// ---------------------------------------------------------------------------
// k_attn: partial flash attention over a 512-column chunk.
// Grid (32, 8); 512 threads. BM=128 rows, BN=64 per tile (8 tiles).
// ty=tid>>4 (0..31): rows 4ty..+3; tx=tid&15: QK cols 4tx..+3, PV d-cols
// {4tx..+3, 64+4tx..+3}.  LDS 130KB: Qs[d][r] 128x128, Ks[d][j] 128x68
// (overlaid by Ps[r][j] 128x68 after QK), Vs[j][d] 64x128.
// ---------------------------------------------------------------------------
__global__ __launch_bounds__(512) void k_attn(
    const float* __restrict__ QhT, const float* __restrict__ KhT,
    const float* __restrict__ Vh, const float* __restrict__ adj,
    float* __restrict__ xp0, float* __restrict__ xp1, float* __restrict__ xp2,
    float* __restrict__ xp3, float* __restrict__ xp4, float* __restrict__ xp5,
    float* __restrict__ xp6, float* __restrict__ xp7,
    float* __restrict__ ml) {
  __shared__ float Qs[128 * 128];
  __shared__ float Ks[128 * 68];
  __shared__ float Vs[64 * 128];
  int i0 = blockIdx.x * 128;
  int cid = blockIdx.y;
  int tid = threadIdx.x;
  int ty = tid >> 4, tx = tid & 15;
  float* xp = (cid < 4) ? ((cid < 2) ? (cid == 0 ? xp0 : xp1) : (cid == 2 ? xp2 : xp3))
                        : ((cid < 6) ? (cid == 4 ? xp4 : xp5) : (cid == 6 ? xp6 : xp7));

  // stage Q once: [d][r], 4096 float4s
#pragma unroll
  for (int s = 0; s < 8; ++s) {
    int f4 = tid + 512 * s;
    int d = f4 >> 5, r4 = (f4 & 31) << 2;
    *(float4*)&Qs[d * 128 + r4] = *(const float4*)&QhT[d * N + i0 + r4];
  }

  float m[4], l[4], X[4][8];
#pragma unroll
  for (int i = 0; i < 4; ++i) {
    m[i] = -3.0e38f; l[i] = 0.f;
#pragma unroll
    for (int c = 0; c < 8; ++c) X[i][c] = 0.f;
  }

  for (int jt = 0; jt < 8; ++jt) {
    int j0g = cid * (N / CSPLIT) + jt * 64;
    // prefetch adj mask into regs (latency hides under staging)
    float4 adjv[4];
#pragma unroll
    for (int i = 0; i < 4; ++i)
      adjv[i] = *(const float4*)&adj[(i0 + 4 * ty + i) * N + j0g + 4 * tx];
    __syncthreads();       // prior PV reads of Ks/Vs done; Qs staged (iter 0)
#pragma unroll
    for (int s = 0; s < 4; ++s) {
      int f4 = tid + 512 * s;
      int d = f4 >> 4, j4 = (f4 & 15) << 2;
      *(float4*)&Ks[d * 68 + j4] = *(const float4*)&KhT[d * N + j0g + j4];
    }
#pragma unroll
    for (int s = 0; s < 4; ++s) {
      int f4 = tid + 512 * s;
      int j = f4 >> 5, d4 = (f4 & 31) << 2;
      *(float4*)&Vs[j * 128 + d4] = *(const float4*)&Vh[(j0g + j) * NH + d4];
    }
    __syncthreads();

    // QK^T: 4x4 per thread
    float sm[4][4];
#pragma unroll
    for (int i = 0; i < 4; ++i)
#pragma unroll
      for (int c = 0; c < 4; ++c) sm[i][c] = 0.f;
#pragma unroll 8
    for (int k = 0; k < 128; ++k) {
      const float4 qv = *(const float4*)&Qs[k * 128 + 4 * ty];
      const float4 kv = *(const float4*)&Ks[k * 68 + 4 * tx];
#pragma unroll
      for (int i = 0; i < 4; ++i) {
        float q = ((const float*)&qv)[i];
        sm[i][0] += q * kv.x; sm[i][1] += q * kv.y;
        sm[i][2] += q * kv.z; sm[i][3] += q * kv.w;
      }
    }
    // mask + online softmax (row groups of 16 lanes = tx)
    float p[4][4];
#pragma unroll
    for (int i = 0; i < 4; ++i) {
      float a0 = sm[i][0] * adjv[i].x;
      float a1 = sm[i][1] * adjv[i].y;
      float a2 = sm[i][2] * adjv[i].z;
      float a3 = sm[i][3] * adjv[i].w;
      float t = fmaxf(fmaxf(a0, a1), fmaxf(a2, a3));
      t = fmaxf(t, __shfl_xor(t, 1));
      t = fmaxf(t, __shfl_xor(t, 2));
      t = fmaxf(t, __shfl_xor(t, 4));
      t = fmaxf(t, __shfl_xor(t, 8));
      float mn = fmaxf(m[i], t);
      float sc = __expf(m[i] - mn);
      p[i][0] = __expf(a0 - mn); p[i][1] = __expf(a1 - mn);
      p[i][2] = __expf(a2 - mn); p[i][3] = __expf(a3 - mn);
      float ps = p[i][0] + p[i][1] + p[i][2] + p[i][3];
      ps += __shfl_xor(ps, 1);
      ps += __shfl_xor(ps, 2);
      ps += __shfl_xor(ps, 4);
      ps += __shfl_xor(ps, 8);
      l[i] = l[i] * sc + ps;
      m[i] = mn;
#pragma unroll
      for (int c = 0; c < 8; ++c) X[i][c] *= sc;
    }
    __syncthreads();       // QK reads of Ks complete
    // write P (row-major) over the Ks region
#pragma unroll
    for (int i = 0; i < 4; ++i) {
      float4 pv = {p[i][0], p[i][1], p[i][2], p[i][3]};
      *(float4*)&Ks[(4 * ty + i) * 68 + 4 * tx] = pv;
    }
    __syncthreads();

    // PV: 4 rows x 8 d-cols per thread
#pragma unroll 2
    for (int j0 = 0; j0 < 64; j0 += 4) {
      float4 pr[4];
#pragma unroll
      for (int i = 0; i < 4; ++i)
        pr[i] = *(const float4*)&Ks[(4 * ty + i) * 68 + j0];
#pragma unroll
      for (int jj = 0; jj < 4; ++jj) {
        const float4 v0 = *(const float4*)&Vs[(j0 + jj) * 128 + 4 * tx];
        const float4 v1 = *(const float4*)&Vs[(j0 + jj) * 128 + 64 + 4 * tx];
#pragma unroll
        for (int i = 0; i < 4; ++i) {
          float pj = ((const float*)&pr[i])[jj];
          X[i][0] += pj * v0.x; X[i][1] += pj * v0.y;
          X[i][2] += pj * v0.z; X[i][3] += pj * v0.w;
          X[i][4] += pj * v1.x; X[i][5] += pj * v1.y;
          X[i][6] += pj * v1.z; X[i][7] += pj * v1.w;
        }
      }
    }
  }

#pragma unroll
  for (int i = 0; i < 4; ++i) {
    int row = i0 + 4 * ty + i;
    float4 o0 = {X[i][0], X[i][1], X[i][2], X[i][3]};
    float4 o1 = {X[i][4], X[i][5], X[i][6], X[i][7]};
    *(float4*)&xp[row * NH + 4 * tx] = o0;
    *(float4*)&xp[row * NH + 64 + 4 * tx] = o1;
    if (tx == 0) {
      ml[(cid * N + row) * 2 + 0] = m[i];
      ml[(cid * N + row) * 2 + 1] = l[i];
    }
  }
}

// ---------------------------------------------------------------------------
// k_comb: merge 8 chunk-partials, normalize, relu -> Xt (in-place ok for xp7)
// ---------------------------------------------------------------------------
__global__ void k_comb(const float* __restrict__ xp0, const float* __restrict__ xp1,
                       const float* __restrict__ xp2, const float* __restrict__ xp3,
                       const float* __restrict__ xp4, const float* __restrict__ xp5,
                       const float* __restrict__ xp6, const float* __restrict__ xp7,
                       const float* __restrict__ ml, float* __restrict__ Xt) {
  int idx = blockIdx.x * 256 + threadIdx.x;
  int r = idx >> 5, d4 = (idx & 31) << 2;
  float mm[8], ll[8];
#pragma unroll
  for (int c = 0; c < 8; ++c) {
    mm[c] = ml[(c * N + r) * 2 + 0];
    ll[c] = ml[(c * N + r) * 2 + 1];
  }
  float ms = mm[0];
#pragma unroll
  for (int c = 1; c < 8; ++c) ms = fmaxf(ms, mm[c]);
  float e[8], den = 0.f;
#pragma unroll
  for (int c = 0; c < 8; ++c) { e[c] = __expf(mm[c] - ms); den += e[c] * ll[c]; }
  float inv = 1.f / den;
  const float4 a0 = *(const float4*)&xp0[r * NH + d4];
  const float4 a1 = *(const float4*)&xp1[r * NH + d4];
  const float4 a2 = *(const float4*)&xp2[r * NH + d4];
  const float4 a3 = *(const float4*)&xp3[r * NH + d4];
  const float4 a4 = *(const float4*)&xp4[r * NH + d4];
  const float4 a5 = *(const float4*)&xp5[r * NH + d4];
  const float4 a6 = *(const float4*)&xp6[r * NH + d4];
  const float4 a7 = *(const float4*)&xp7[r * NH + d4];
  float4 o;
  o.x = a0.x * e[0] + a1.x * e[1] + a2.x * e[2] + a3.x * e[3]
      + a4.x * e[4] + a5.x * e[5] + a6.x * e[6] + a7.x * e[7];
  o.y = a0.y * e[0] + a1.y * e[1] + a2.y * e[2] + a3.y * e[3]
      + a4.y * e[4] + a5.y * e[5] + a6.y * e[6] + a7.y * e[7];
  o.z = a0.z * e[0] + a1.z * e[1] + a2.z * e[2] + a3.z * e[3]
      + a4.z * e[4] + a5.z * e[5] + a6.z * e[6] + a7.z * e[7];
  o.w = a0.w * e[0] + a1.w * e[1] + a2.w * e[2] + a3.w * e[3]
      + a4.w * e[4] + a5.w * e[5] + a6.w * e[6] + a7.w * e[7];
  o.x = fmaxf(o.x * inv, 0.f); o.y = fmaxf(o.y * inv, 0.f);
  o.z = fmaxf(o.z * inv, 0.f); o.w = fmaxf(o.w * inv, 0.f);
  *(float4*)&Xt[r * NH + d4] = o;
}

// ---------------------------------------------------------------------------
// k_xtw2: xtw2 = Xt @ W2
// ---------------------------------------------------------------------------
__global__ void k_xtw2(const float* __restrict__ Xt, const float* __restrict__ W2,
                       float* __restrict__ xtw2) {
  int i = blockIdx.x * 16 + (threadIdx.x >> 4);
  int c = threadIdx.x & 15;
  float acc = 0.f;
  for (int k = 0; k < NH; ++k) acc += Xt[i * NH + k] * W2[k * NC + c];
  xtw2[i * NC + c] = acc;
}

// ---------------------------------------------------------------------------
// k_z: z = adj @ xtw2 + b2; out = rowsoftmax(z).
// Grid 256 blocks (BM=16 rows), 256 threads: ty=tid>>6 (4 rows), cg=(tid>>4)&3
// (4 classes), jg=tid&15 (4-j slice). adj read as float4 from global (L3);
// xtw2 staged transposed [c][j] stride 68.
// ---------------------------------------------------------------------------
__global__ __launch_bounds__(256) void k_z(const float* __restrict__ adj,
                                           const float* __restrict__ xtw2,
                                           const float* __restrict__ b2,
                                           float* __restrict__ out) {
  __shared__ float xwsT[16 * 68];
  int i0 = blockIdx.x * 16;
  int tid = threadIdx.x;
  int ty = tid >> 6, cg = (tid >> 4) & 3, jg = tid & 15;
  int jr = tid >> 2, cq = tid & 3;
  float acc[4][4];
#pragma unroll
  for (int i = 0; i < 4; ++i)
#pragma unroll
    for (int c = 0; c < 4; ++c) acc[i][c] = 0.f;

  for (int j0 = 0; j0 < N; j0 += 64) {
    // prefetch adj rows (global f4) + xtw2 stage value
    float4 av[4];
#pragma unroll
    for (int i = 0; i < 4; ++i)
      av[i] = *(const float4*)&adj[(i0 + 4 * ty + i) * N + j0 + 4 * jg];
    const float4 xv = *(const float4*)&xtw2[(j0 + jr) * NC + 4 * cq];
    __syncthreads();          // previous chunk's reads of xwsT done
    xwsT[(4 * cq + 0) * 68 + jr] = xv.x;
    xwsT[(4 * cq + 1) * 68 + jr] = xv.y;
    xwsT[(4 * cq + 2) * 68 + jr] = xv.z;
    xwsT[(4 * cq + 3) * 68 + jr] = xv.w;
    __syncthreads();
#pragma unroll
    for (int c = 0; c < 4; ++c) {
      const float4 wv = *(const float4*)&xwsT[(4 * cg + c) * 68 + 4 * jg];
#pragma unroll
      for (int i = 0; i < 4; ++i)
        acc[i][c] += av[i].x * wv.x + av[i].y * wv.y
                   + av[i].z * wv.z + av[i].w * wv.w;
    }
  }
  // reduce over jg (low 4 lane bits)
#pragma unroll
  for (int i = 0; i < 4; ++i)
#pragma unroll
    for (int c = 0; c < 4; ++c) {
      float v = acc[i][c];
      v += __shfl_xor(v, 1);
      v += __shfl_xor(v, 2);
      v += __shfl_xor(v, 4);
      v += __shfl_xor(v, 8);
      acc[i][c] = v;
    }
  float bv0 = b2[4 * cg + 0], bv1 = b2[4 * cg + 1];
  float bv2 = b2[4 * cg + 2], bv3 = b2[4 * cg + 3];
#pragma unroll
  for (int i = 0; i < 4; ++i) {
    float z0 = acc[i][0] + bv0, z1 = acc[i][1] + bv1;
    float z2 = acc[i][2] + bv2, z3 = acc[i][3] + bv3;
    float mv = fmaxf(fmaxf(z0, z1), fmaxf(z2, z3));
    mv = fmaxf(mv, __shfl_xor(mv, 16));
    mv = fmaxf(mv, __shfl_xor(mv, 32));
    float e0 = __expf(z0 - mv), e1 = __expf(z1 - mv);
    float e2 = __expf(z2 - mv), e3 = __expf(z3 - mv);
    float s = e0 + e1 + e2 + e3;
    s += __shfl_xor(s, 16);
    s += __shfl_xor(s, 32);
    if (jg == 0) {
      float4 o = {e0 / s, e1 / s, e2 / s, e3 / s};
      *(float4*)&out[(i0 + 4 * ty + i) * NC + 4 * cg] = o;
    }
  }
}

// ---------------------------------------------------------------------------
extern "C" void kernel_launch(void* const* d_in, const int* in_sizes, int n_in,
                              void* d_out, int out_size, void* d_ws, size_t ws_size,
                              hipStream_t stream) {
  const float* A0  = (const float*)d_in[0];
  const float* A1  = (const float*)d_in[1];
  const float* A2  = (const float*)d_in[2];
  const float* x   = (const float*)d_in[3];
  const float* Wa1 = (const float*)d_in[4];  const float* ba1 = (const float*)d_in[5];
  const float* Wa2 = (const float*)d_in[6];  const float* ba2 = (const float*)d_in[7];
  const float* Wa3 = (const float*)d_in[8];  const float* ba3 = (const float*)d_in[9];
  const float* Wagg = (const float*)d_in[10]; const float* bagg = (const float*)d_in[11];
  const float* W1  = (const float*)d_in[12]; const float* b1  = (const float*)d_in[13];
  const float* Wq  = (const float*)d_in[14]; const float* bq  = (const float*)d_in[15];
  const float* Wk  = (const float*)d_in[16]; const float* bk  = (const float*)d_in[17];
  const float* Wv  = (const float*)d_in[18]; const float* bv  = (const float*)d_in[19];
  const float* W2  = (const float*)d_in[20]; const float* b2  = (const float*)d_in[21];

  float* out0 = (float*)d_out;            // [N,16] class softmax
  float* nz   = out0 + N * NC;            // [N,3] mixing weights (output 1)

  float* ws   = (float*)d_ws;
  float* adj  = ws;                       // N*N
  float* Wc   = adj + (size_t)N * N;      // 3*N*3
  float* bz   = Wc + 3 * N * 3;           // 16
  float* xw1  = bz + 16;                  // N*NH  (attn partial 0)
  float* hpre = xw1 + N * NH;             // N*NH  (attn partial 1)
  float* QhT  = hpre + N * NH;            // N*NH  transposed [128][4096]
  float* KhT  = QhT + N * NH;             // N*NH  transposed [128][4096]
  float* Vh   = KhT + N * NH;             // N*NH
  float* Xt   = Vh + N * NH;              // N*NH  (attn partial 7)
  float* xtw2 = Xt + N * NH;              // N*NC
  float* P2   = xtw2 + N * NC;            // 5 extra partials
  float* P3   = P2 + N * NH;
  float* P4   = P3 + N * NH;
  float* P5   = P4 + N * NH;
  float* P6   = P5 + N * NH;
  float* ml   = P6 + N * NH;              // 8*N*2

  hipLaunchKernelGGL(k_wc, dim3(48), dim3(256), 0, stream,
                     Wa1, Wa2, Wa3, Wagg, ba1, ba2, ba3, bagg, Wc, bz);
  hipLaunchKernelGGL(k_z4nz, dim3(N / 16), dim3(256), 0, stream,
                     A0, A1, A2, Wc, bz, nz);
  hipLaunchKernelGGL(k_adj, dim3(N * N / 4 / 256), dim3(256), 0, stream,
                     A0, A1, A2, nz, adj);
  hipLaunchKernelGGL(k_xw1, dim3(N / 16), dim3(128), 0, stream, x, W1, xw1);
  hipLaunchKernelGGL(k_hinit, dim3(N * NH / 256), dim3(256), 0, stream, b1, hpre);
  hipLaunchKernelGGL(k_h, dim3(N / 128, 8), dim3(256), 0, stream, adj, xw1, hpre);
  hipLaunchKernelGGL(k_qkv, dim3(N / 16), dim3(128), 0, stream,
                     hpre, Wq, bq, Wk, bk, Wv, bv, QhT, KhT, Vh);
  hipLaunchKernelGGL(k_attn, dim3(N / 128, CSPLIT), dim3(512), 0, stream,
                     QhT, KhT, Vh, adj, xw1, hpre, P2, P3, P4, P5, P6, Xt, ml);
  hipLaunchKernelGGL(k_comb, dim3(N * NH / 4 / 256), dim3(256), 0, stream,
                     xw1, hpre, P2, P3, P4, P5, P6, Xt, ml, Xt);
  hipLaunchKernelGGL(k_xtw2, dim3(N / 16), dim3(256), 0, stream, Xt, W2, xtw2);
  hipLaunchKernelGGL(k_z, dim3(N / 16), dim3(256), 0, stream, adj, xtw2, b2, out0);
}

// Round 4
// 477.281 us; speedup vs baseline: 4.5307x; 1.3335x over previous
//
#include <hip/hip_runtime.h>
#include <math.h>

#define N 4096
#define NF 512
#define NH 128
#define NC 16
#define CSPLIT 8

// ---------------------------------------------------------------------------
// k_wc: Wc_k[j,c] = sum_t Wa_k[j,t] * Wagg[k*64+t, c]   (3*N*3 values)
// ---------------------------------------------------------------------------
__global__ void k_wc(const float* __restrict__ Wa1, const float* __restrict__ Wa2,
                     const float* __restrict__ Wa3, const float* __restrict__ Wagg,
                     const float* __restrict__ ba1, const float* __restrict__ ba2,
                     const float* __restrict__ ba3, const float* __restrict__ bagg,
                     float* __restrict__ Wc, float* __restrict__ bz) {
  int idx = blockIdx.x * 256 + threadIdx.x;
  if (idx < 3 * N) {
    int k = idx >> 12;
    int j = idx & (N - 1);
    const float* Wa = (k == 0) ? Wa1 : (k == 1) ? Wa2 : Wa3;
    float a0 = 0.f, a1 = 0.f, a2 = 0.f;
    for (int t = 0; t < 64; ++t) {
      float w = Wa[j * 64 + t];
      const float* wg = Wagg + (k * 64 + t) * 3;
      a0 += w * wg[0]; a1 += w * wg[1]; a2 += w * wg[2];
    }
    float* o = Wc + j * 9 + k * 3;
    o[0] = a0; o[1] = a1; o[2] = a2;
  }
  if (blockIdx.x == 0 && threadIdx.x < 3) {
    int c = threadIdx.x;
    float acc = bagg[c];
    for (int t = 0; t < 64; ++t) {
      acc += ba1[t] * Wagg[t * 3 + c]
           + ba2[t] * Wagg[(64 + t) * 3 + c]
           + ba3[t] * Wagg[(128 + t) * 3 + c];
    }
    bz[c] = acc;
  }
}

// ---------------------------------------------------------------------------
// k_z4p: partial z4 over a 1024-column chunk.
// Grid (512, 4), 256 threads. 8 rows/block; thread owns one float4 col slot.
// zp[row*12 + chunk*3 + c] partial sums.
// ---------------------------------------------------------------------------
__global__ __launch_bounds__(256, 4) void k_z4p(
    const float* __restrict__ A0, const float* __restrict__ A1,
    const float* __restrict__ A2, const float* __restrict__ Wc,
    float* __restrict__ zp) {
  __shared__ float red[8][3][4];
  int i0 = blockIdx.x * 8;
  int c0 = blockIdx.y * 1024;
  int tid = threadIdx.x;
  int j4 = c0 + tid * 4;
  float w[36];
#pragma unroll
  for (int q = 0; q < 9; ++q) {
    const float4 v = *(const float4*)&Wc[j4 * 9 + q * 4];
    w[4 * q] = v.x; w[4 * q + 1] = v.y; w[4 * q + 2] = v.z; w[4 * q + 3] = v.w;
  }
  float acc[8][3];
#pragma unroll
  for (int r = 0; r < 8; ++r) { acc[r][0] = 0.f; acc[r][1] = 0.f; acc[r][2] = 0.f; }
#pragma unroll
  for (int r = 0; r < 8; ++r) {
    const float4 a0 = *(const float4*)&A0[(i0 + r) * N + j4];
    const float4 a1 = *(const float4*)&A1[(i0 + r) * N + j4];
    const float4 a2 = *(const float4*)&A2[(i0 + r) * N + j4];
#pragma unroll
    for (int jj = 0; jj < 4; ++jj) {
      float x0 = ((const float*)&a0)[jj];
      float x1 = ((const float*)&a1)[jj];
      float x2 = ((const float*)&a2)[jj];
#pragma unroll
      for (int cc = 0; cc < 3; ++cc)
        acc[r][cc] += x0 * w[jj * 9 + cc] + x1 * w[jj * 9 + 3 + cc]
                    + x2 * w[jj * 9 + 6 + cc];
    }
  }
  int lane = tid & 63, wv = tid >> 6;
#pragma unroll
  for (int r = 0; r < 8; ++r) {
#pragma unroll
    for (int c = 0; c < 3; ++c) {
      float v = acc[r][c];
      v += __shfl_down(v, 32);
      v += __shfl_down(v, 16);
      v += __shfl_down(v, 8);
      v += __shfl_down(v, 4);
      v += __shfl_down(v, 2);
      v += __shfl_down(v, 1);
      if (lane == 0) red[r][c][wv] = v;
    }
  }
  __syncthreads();
  if (tid < 8) {
#pragma unroll
    for (int c = 0; c < 3; ++c) {
      float v = red[tid][c][0] + red[tid][c][1] + red[tid][c][2] + red[tid][c][3];
      zp[(i0 + tid) * 12 + blockIdx.y * 3 + c] = v;
    }
  }
}

// ---------------------------------------------------------------------------
// k_nz: finalize z4 (sum 4 chunk partials + bz) and 3-way softmax -> nz
// ---------------------------------------------------------------------------
__global__ void k_nz(const float* __restrict__ zp, const float* __restrict__ bz,
                     float* __restrict__ nz) {
  int row = blockIdx.x * 256 + threadIdx.x;
  const float* p = zp + row * 12;
  float z0 = p[0] + p[3] + p[6] + p[9] + bz[0];
  float z1 = p[1] + p[4] + p[7] + p[10] + bz[1];
  float z2 = p[2] + p[5] + p[8] + p[11] + bz[2];
  float m = fmaxf(z0, fmaxf(z1, z2));
  float e0 = __expf(z0 - m), e1 = __expf(z1 - m), e2 = __expf(z2 - m);
  float s = e0 + e1 + e2;
  float* o = nz + row * 3;
  o[0] = e0 / s; o[1] = e1 / s; o[2] = e2 / s;
}

// ---------------------------------------------------------------------------
// k_adj: adj[i,j] = A0*nz[j,0] + A1*nz[j,1] + A2*nz[j,2]  (column-broadcast)
// ---------------------------------------------------------------------------
__global__ void k_adj(const float* __restrict__ A0, const float* __restrict__ A1,
                      const float* __restrict__ A2, const float* __restrict__ nz,
                      float* __restrict__ adj) {
  int idx = blockIdx.x * 256 + threadIdx.x;
  int i = idx >> 10;
  int j4 = (idx & 1023) << 2;
  int base = i * N + j4;
  const float4 a0 = *(const float4*)&A0[base];
  const float4 a1 = *(const float4*)&A1[base];
  const float4 a2 = *(const float4*)&A2[base];
  const float4 n0 = *(const float4*)&nz[j4 * 3];
  const float4 n1 = *(const float4*)&nz[j4 * 3 + 4];
  const float4 n2 = *(const float4*)&nz[j4 * 3 + 8];
  float4 o;
  o.x = a0.x * n0.x + a1.x * n0.y + a2.x * n0.z;
  o.y = a0.y * n0.w + a1.y * n1.x + a2.y * n1.y;
  o.z = a0.z * n1.z + a1.z * n1.w + a2.z * n2.x;
  o.w = a0.w * n2.y + a1.w * n2.z + a2.w * n2.w;
  *(float4*)&adj[base] = o;
}

// ---------------------------------------------------------------------------
// k_xw1: xw1 = x @ W1.  8 rows/block, 512 blocks, 128 threads.
// ---------------------------------------------------------------------------
__global__ void k_xw1(const float* __restrict__ x, const float* __restrict__ W1,
                      float* __restrict__ xw1) {
  __shared__ float xs[8][NF];
  int i0 = blockIdx.x * 8;
  int tid = threadIdx.x;
  for (int l = tid; l < 8 * NF; l += 128) {
    int r = l >> 9, k = l & (NF - 1);
    xs[r][k] = x[(i0 + r) * NF + k];
  }
  __syncthreads();
  float acc[8];
#pragma unroll
  for (int r = 0; r < 8; ++r) acc[r] = 0.f;
#pragma unroll 4
  for (int k = 0; k < NF; ++k) {
    float w = W1[k * NH + tid];
#pragma unroll
    for (int r = 0; r < 8; ++r) acc[r] += xs[r][k] * w;
  }
  for (int r = 0; r < 8; ++r) xw1[(i0 + r) * NH + tid] = acc[r];
}

__global__ void k_hinit(const float* __restrict__ b1, float* __restrict__ hpre) {
  int idx = blockIdx.x * 256 + threadIdx.x;
  if (idx < N * NH) hpre[idx] = b1[idx & (NH - 1)];
}

// ---------------------------------------------------------------------------
// k_h: hpre += adj @ xw1.  Grid (32, 8) = 256 blocks, 256 threads.
// ---------------------------------------------------------------------------
__global__ __launch_bounds__(256) void k_h(const float* __restrict__ adj,
                                           const float* __restrict__ xw1,
                                           float* __restrict__ hpre) {
  __shared__ float adjT[64 * 132];
  __shared__ float xw1s[64 * 132];
  int i0 = blockIdx.x * 128;
  int kbase = blockIdx.y * 512;
  int tid = threadIdx.x;
  int ty = tid >> 4, tx = tid & 15;
  float acc[8][8];
#pragma unroll
  for (int i = 0; i < 8; ++i)
#pragma unroll
    for (int c = 0; c < 8; ++c) acc[i][c] = 0.f;

  int rs = tid >> 1, kh = (tid & 1) * 32;
  for (int t = 0; t < 8; ++t) {
    int k0 = kbase + t * 64;
    __syncthreads();
#pragma unroll
    for (int q = 0; q < 8; ++q) {
      int k4 = kh + q * 4;
      const float4 v = *(const float4*)&adj[(i0 + rs) * N + k0 + k4];
      adjT[(k4 + 0) * 132 + rs] = v.x;
      adjT[(k4 + 1) * 132 + rs] = v.y;
      adjT[(k4 + 2) * 132 + rs] = v.z;
      adjT[(k4 + 3) * 132 + rs] = v.w;
    }
#pragma unroll
    for (int s = 0; s < 8; ++s) {
      int f4 = tid + 256 * s;
      int k = f4 >> 5, c4 = (f4 & 31) << 2;
      *(float4*)&xw1s[k * 132 + c4] = *(const float4*)&xw1[(k0 + k) * NH + c4];
    }
    __syncthreads();
#pragma unroll 4
    for (int k = 0; k < 64; ++k) {
      const float4 a0 = *(const float4*)&adjT[k * 132 + 8 * ty];
      const float4 a1 = *(const float4*)&adjT[k * 132 + 8 * ty + 4];
      const float4 w0 = *(const float4*)&xw1s[k * 132 + 4 * tx];
      const float4 w1 = *(const float4*)&xw1s[k * 132 + 64 + 4 * tx];
#pragma unroll
      for (int i = 0; i < 4; ++i) {
        float ai = ((const float*)&a0)[i];
        acc[i][0] += ai * w0.x; acc[i][1] += ai * w0.y;
        acc[i][2] += ai * w0.z; acc[i][3] += ai * w0.w;
        acc[i][4] += ai * w1.x; acc[i][5] += ai * w1.y;
        acc[i][6] += ai * w1.z; acc[i][7] += ai * w1.w;
        float bi = ((const float*)&a1)[i];
        acc[4 + i][0] += bi * w0.x; acc[4 + i][1] += bi * w0.y;
        acc[4 + i][2] += bi * w0.z; acc[4 + i][3] += bi * w0.w;
        acc[4 + i][4] += bi * w1.x; acc[4 + i][5] += bi * w1.y;
        acc[4 + i][6] += bi * w1.z; acc[4 + i][7] += bi * w1.w;
      }
    }
  }
#pragma unroll
  for (int i = 0; i < 8; ++i) {
    int row = i0 + 8 * ty + i;
#pragma unroll
    for (int c = 0; c < 4; ++c)
      atomicAdd(&hpre[row * NH + 4 * tx + c], acc[i][c]);
#pragma unroll
    for (int c = 0; c < 4; ++c)
      atomicAdd(&hpre[row * NH + 64 + 4 * tx + c], acc[i][4 + c]);
  }
}

// ---------------------------------------------------------------------------
// k_qkv: h = relu(hpre); QhT/KhT (transposed, d-major) and Vh (row-major).
// 8 rows/block, 512 blocks, 128 threads.
// ---------------------------------------------------------------------------
__global__ void k_qkv(const float* __restrict__ hpre,
                      const float* __restrict__ Wq, const float* __restrict__ bq,
                      const float* __restrict__ Wk, const float* __restrict__ bk,
                      const float* __restrict__ Wv, const float* __restrict__ bv,
                      float* __restrict__ QhT, float* __restrict__ KhT,
                      float* __restrict__ Vh) {
  __shared__ float hs[8][NH];
  int i0 = blockIdx.x * 8;
  int tid = threadIdx.x;
  for (int l = tid; l < 8 * NH; l += 128) {
    int r = l >> 7, k = l & (NH - 1);
    hs[r][k] = fmaxf(hpre[(i0 + r) * NH + k], 0.f);
  }
  __syncthreads();
  float aq[8], ak[8], av[8];
#pragma unroll
  for (int r = 0; r < 8; ++r) { aq[r] = 0.f; ak[r] = 0.f; av[r] = 0.f; }
#pragma unroll 4
  for (int k = 0; k < NH; ++k) {
    float wq = Wq[k * NH + tid];
    float wk = Wk[k * NH + tid];
    float wv = Wv[k * NH + tid];
#pragma unroll
    for (int r = 0; r < 8; ++r) {
      float h = hs[r][k];
      aq[r] += h * wq; ak[r] += h * wk; av[r] += h * wv;
    }
  }
  float bqv = bq[tid], bkv = bk[tid], bvv = bv[tid];
#pragma unroll
  for (int r = 0; r < 8; r += 4) {
    float4 q = {aq[r] + bqv, aq[r + 1] + bqv, aq[r + 2] + bqv, aq[r + 3] + bqv};
    float4 k4 = {ak[r] + bkv, ak[r + 1] + bkv, ak[r + 2] + bkv, ak[r + 3] + bkv};
    *(float4*)&QhT[tid * N + i0 + r] = q;
    *(float4*)&KhT[tid * N + i0 + r] = k4;
  }
  for (int r = 0; r < 8; ++r) Vh[(i0 + r) * NH + tid] = av[r] + bvv;
}

// ---------------------------------------------------------------------------
// k_attn: partial flash attention over a 512-column chunk.
// Grid (32, 8); 512 threads. BM=128 rows, BN=64 per tile (8 tiles).
// ---------------------------------------------------------------------------
__global__ __launch_bounds__(512) void k_attn(
    const float* __restrict__ QhT, const float* __restrict__ KhT,
    const float* __restrict__ Vh, const float* __restrict__ adj,
    float* __restrict__ xp0, float* __restrict__ xp1, float* __restrict__ xp2,
    float* __restrict__ xp3, float* __restrict__ xp4, float* __restrict__ xp5,
    float* __restrict__ xp6, float* __restrict__ xp7,
    float* __restrict__ ml) {
  __shared__ float Qs[128 * 128];
  __shared__ float Ks[128 * 68];
  __shared__ float Vs[64 * 128];
  int i0 = blockIdx.x * 128;
  int cid = blockIdx.y;
  int tid = threadIdx.x;
  int ty = tid >> 4, tx = tid & 15;
  float* xp = (cid < 4) ? ((cid < 2) ? (cid == 0 ? xp0 : xp1) : (cid == 2 ? xp2 : xp3))
                        : ((cid < 6) ? (cid == 4 ? xp4 : xp5) : (cid == 6 ? xp6 : xp7));

#pragma unroll
  for (int s = 0; s < 8; ++s) {
    int f4 = tid + 512 * s;
    int d = f4 >> 5, r4 = (f4 & 31) << 2;
    *(float4*)&Qs[d * 128 + r4] = *(const float4*)&QhT[d * N + i0 + r4];
  }

  float m[4], l[4], X[4][8];
#pragma unroll
  for (int i = 0; i < 4; ++i) {
    m[i] = -3.0e38f; l[i] = 0.f;
#pragma unroll
    for (int c = 0; c < 8; ++c) X[i][c] = 0.f;
  }

  for (int jt = 0; jt < 8; ++jt) {
    int j0g = cid * (N / CSPLIT) + jt * 64;
    float4 adjv[4];
#pragma unroll
    for (int i = 0; i < 4; ++i)
      adjv[i] = *(const float4*)&adj[(i0 + 4 * ty + i) * N + j0g + 4 * tx];
    __syncthreads();
#pragma unroll
    for (int s = 0; s < 4; ++s) {
      int f4 = tid + 512 * s;
      int d = f4 >> 4, j4 = (f4 & 15) << 2;
      *(float4*)&Ks[d * 68 + j4] = *(const float4*)&KhT[d * N + j0g + j4];
    }
#pragma unroll
    for (int s = 0; s < 4; ++s) {
      int f4 = tid + 512 * s;
      int j = f4 >> 5, d4 = (f4 & 31) << 2;
      *(float4*)&Vs[j * 128 + d4] = *(const float4*)&Vh[(j0g + j) * NH + d4];
    }
    __syncthreads();

    float sm[4][4];
#pragma unroll
    for (int i = 0; i < 4; ++i)
#pragma unroll
      for (int c = 0; c < 4; ++c) sm[i][c] = 0.f;
#pragma unroll 8
    for (int k = 0; k < 128; ++k) {
      const float4 qv = *(const float4*)&Qs[k * 128 + 4 * ty];
      const float4 kv = *(const float4*)&Ks[k * 68 + 4 * tx];
#pragma unroll
      for (int i = 0; i < 4; ++i) {
        float q = ((const float*)&qv)[i];
        sm[i][0] += q * kv.x; sm[i][1] += q * kv.y;
        sm[i][2] += q * kv.z; sm[i][3] += q * kv.w;
      }
    }
    float p[4][4];
#pragma unroll
    for (int i = 0; i < 4; ++i) {
      float a0 = sm[i][0] * adjv[i].x;
      float a1 = sm[i][1] * adjv[i].y;
      float a2 = sm[i][2] * adjv[i].z;
      float a3 = sm[i][3] * adjv[i].w;
      float t = fmaxf(fmaxf(a0, a1), fmaxf(a2, a3));
      t = fmaxf(t, __shfl_xor(t, 1));
      t = fmaxf(t, __shfl_xor(t, 2));
      t = fmaxf(t, __shfl_xor(t, 4));
      t = fmaxf(t, __shfl_xor(t, 8));
      float mn = fmaxf(m[i], t);
      float sc = __expf(m[i] - mn);
      p[i][0] = __expf(a0 - mn); p[i][1] = __expf(a1 - mn);
      p[i][2] = __expf(a2 - mn); p[i][3] = __expf(a3 - mn);
      float ps = p[i][0] + p[i][1] + p[i][2] + p[i][3];
      ps += __shfl_xor(ps, 1);
      ps += __shfl_xor(ps, 2);
      ps += __shfl_xor(ps, 4);
      ps += __shfl_xor(ps, 8);
      l[i] = l[i] * sc + ps;
      m[i] = mn;
#pragma unroll
      for (int c = 0; c < 8; ++c) X[i][c] *= sc;
    }
    __syncthreads();
#pragma unroll
    for (int i = 0; i < 4; ++i) {
      float4 pv = {p[i][0], p[i][1], p[i][2], p[i][3]};
      *(float4*)&Ks[(4 * ty + i) * 68 + 4 * tx] = pv;
    }
    __syncthreads();

#pragma unroll 2
    for (int j0 = 0; j0 < 64; j0 += 4) {
      float4 pr[4];
#pragma unroll
      for (int i = 0; i < 4; ++i)
        pr[i] = *(const float4*)&Ks[(4 * ty + i) * 68 + j0];
#pragma unroll
      for (int jj = 0; jj < 4; ++jj) {
        const float4 v0 = *(const float4*)&Vs[(j0 + jj) * 128 + 4 * tx];
        const float4 v1 = *(const float4*)&Vs[(j0 + jj) * 128 + 64 + 4 * tx];
#pragma unroll
        for (int i = 0; i < 4; ++i) {
          float pj = ((const float*)&pr[i])[jj];
          X[i][0] += pj * v0.x; X[i][1] += pj * v0.y;
          X[i][2] += pj * v0.z; X[i][3] += pj * v0.w;
          X[i][4] += pj * v1.x; X[i][5] += pj * v1.y;
          X[i][6] += pj * v1.z; X[i][7] += pj * v1.w;
        }
      }
    }
  }

#pragma unroll
  for (int i = 0; i < 4; ++i) {
    int row = i0 + 4 * ty + i;
    float4 o0 = {X[i][0], X[i][1], X[i][2], X[i][3]};
    float4 o1 = {X[i][4], X[i][5], X[i][6], X[i][7]};
    *(float4*)&xp[row * NH + 4 * tx] = o0;
    *(float4*)&xp[row * NH + 64 + 4 * tx] = o1;
    if (tx == 0) {
      ml[(cid * N + row) * 2 + 0] = m[i];
      ml[(cid * N + row) * 2 + 1] = l[i];
    }
  }
}

// ---------------------------------------------------------------------------
// k_comb: merge 8 chunk-partials, normalize, relu -> Xt
// ---------------------------------------------------------------------------
__global__ void k_comb(const float* __restrict__ xp0, const float* __restrict__ xp1,
                       const float* __restrict__ xp2, const float* __restrict__ xp3,
                       const float* __restrict__ xp4, const float* __restrict__ xp5,
                       const float* __restrict__ xp6, const float* __restrict__ xp7,
                       const float* __restrict__ ml, float* __restrict__ Xt) {
  int idx = blockIdx.x * 256 + threadIdx.x;
  int r = idx >> 5, d4 = (idx & 31) << 2;
  float mm[8], ll[8];
#pragma unroll
  for (int c = 0; c < 8; ++c) {
    mm[c] = ml[(c * N + r) * 2 + 0];
    ll[c] = ml[(c * N + r) * 2 + 1];
  }
  float ms = mm[0];
#pragma unroll
  for (int c = 1; c < 8; ++c) ms = fmaxf(ms, mm[c]);
  float e[8], den = 0.f;
#pragma unroll
  for (int c = 0; c < 8; ++c) { e[c] = __expf(mm[c] - ms); den += e[c] * ll[c]; }
  float inv = 1.f / den;
  const float4 a0 = *(const float4*)&xp0[r * NH + d4];
  const float4 a1 = *(const float4*)&xp1[r * NH + d4];
  const float4 a2 = *(const float4*)&xp2[r * NH + d4];
  const float4 a3 = *(const float4*)&xp3[r * NH + d4];
  const float4 a4 = *(const float4*)&xp4[r * NH + d4];
  const float4 a5 = *(const float4*)&xp5[r * NH + d4];
  const float4 a6 = *(const float4*)&xp6[r * NH + d4];
  const float4 a7 = *(const float4*)&xp7[r * NH + d4];
  float4 o;
  o.x = a0.x * e[0] + a1.x * e[1] + a2.x * e[2] + a3.x * e[3]
      + a4.x * e[4] + a5.x * e[5] + a6.x * e[6] + a7.x * e[7];
  o.y = a0.y * e[0] + a1.y * e[1] + a2.y * e[2] + a3.y * e[3]
      + a4.y * e[4] + a5.y * e[5] + a6.y * e[6] + a7.y * e[7];
  o.z = a0.z * e[0] + a1.z * e[1] + a2.z * e[2] + a3.z * e[3]
      + a4.z * e[4] + a5.z * e[5] + a6.z * e[6] + a7.z * e[7];
  o.w = a0.w * e[0] + a1.w * e[1] + a2.w * e[2] + a3.w * e[3]
      + a4.w * e[4] + a5.w * e[5] + a6.w * e[6] + a7.w * e[7];
  o.x = fmaxf(o.x * inv, 0.f); o.y = fmaxf(o.y * inv, 0.f);
  o.z = fmaxf(o.z * inv, 0.f); o.w = fmaxf(o.w * inv, 0.f);
  *(float4*)&Xt[r * NH + d4] = o;
}

// ---------------------------------------------------------------------------
// k_xtw2: xtw2 = Xt @ W2
// ---------------------------------------------------------------------------
__global__ void k_xtw2(const float* __restrict__ Xt, const float* __restrict__ W2,
                       float* __restrict__ xtw2) {
  int i = blockIdx.x * 16 + (threadIdx.x >> 4);
  int c = threadIdx.x & 15;
  float acc = 0.f;
  for (int k = 0; k < NH; ++k) acc += Xt[i * NH + k] * W2[k * NC + c];
  xtw2[i * NC + c] = acc;
}

// ---------------------------------------------------------------------------
// k_z: z = adj @ xtw2 + b2; out = rowsoftmax(z).
// ---------------------------------------------------------------------------
__global__ __launch_bounds__(256) void k_z(const float* __restrict__ adj,
                                           const float* __restrict__ xtw2,
                                           const float* __restrict__ b2,
                                           float* __restrict__ out) {
  __shared__ float xwsT[16 * 68];
  int i0 = blockIdx.x * 16;
  int tid = threadIdx.x;
  int ty = tid >> 6, cg = (tid >> 4) & 3, jg = tid & 15;
  int jr = tid >> 2, cq = tid & 3;
  float acc[4][4];
#pragma unroll
  for (int i = 0; i < 4; ++i)
#pragma unroll
    for (int c = 0; c < 4; ++c) acc[i][c] = 0.f;

  for (int j0 = 0; j0 < N; j0 += 64) {
    float4 av[4];
#pragma unroll
    for (int i = 0; i < 4; ++i)
      av[i] = *(const float4*)&adj[(i0 + 4 * ty + i) * N + j0 + 4 * jg];
    const float4 xv = *(const float4*)&xtw2[(j0 + jr) * NC + 4 * cq];
    __syncthreads();
    xwsT[(4 * cq + 0) * 68 + jr] = xv.x;
    xwsT[(4 * cq + 1) * 68 + jr] = xv.y;
    xwsT[(4 * cq + 2) * 68 + jr] = xv.z;
    xwsT[(4 * cq + 3) * 68 + jr] = xv.w;
    __syncthreads();
#pragma unroll
    for (int c = 0; c < 4; ++c) {
      const float4 wv = *(const float4*)&xwsT[(4 * cg + c) * 68 + 4 * jg];
#pragma unroll
      for (int i = 0; i < 4; ++i)
        acc[i][c] += av[i].x * wv.x + av[i].y * wv.y
                   + av[i].z * wv.z + av[i].w * wv.w;
    }
  }
#pragma unroll
  for (int i = 0; i < 4; ++i)
#pragma unroll
    for (int c = 0; c < 4; ++c) {
      float v = acc[i][c];
      v += __shfl_xor(v, 1);
      v += __shfl_xor(v, 2);
      v += __shfl_xor(v, 4);
      v += __shfl_xor(v, 8);
      acc[i][c] = v;
    }
  float bv0 = b2[4 * cg + 0], bv1 = b2[4 * cg + 1];
  float bv2 = b2[4 * cg + 2], bv3 = b2[4 * cg + 3];
#pragma unroll
  for (int i = 0; i < 4; ++i) {
    float z0 = acc[i][0] + bv0, z1 = acc[i][1] + bv1;
    float z2 = acc[i][2] + bv2, z3 = acc[i][3] + bv3;
    float mv = fmaxf(fmaxf(z0, z1), fmaxf(z2, z3));
    mv = fmaxf(mv, __shfl_xor(mv, 16));
    mv = fmaxf(mv, __shfl_xor(mv, 32));
    float e0 = __expf(z0 - mv), e1 = __expf(z1 - mv);
    float e2 = __expf(z2 - mv), e3 = __expf(z3 - mv);
    float s = e0 + e1 + e2 + e3;
    s += __shfl_xor(s, 16);
    s += __shfl_xor(s, 32);
    if (jg == 0) {
      float4 o = {e0 / s, e1 / s, e2 / s, e3 / s};
      *(float4*)&out[(i0 + 4 * ty + i) * NC + 4 * cg] = o;
    }
  }
}

// ---------------------------------------------------------------------------
extern "C" void kernel_launch(void* const* d_in, const int* in_sizes, int n_in,
                              void* d_out, int out_size, void* d_ws, size_t ws_size,
                              hipStream_t stream) {
  const float* A0  = (const float*)d_in[0];
  const float* A1  = (const float*)d_in[1];
  const float* A2  = (const float*)d_in[2];
  const float* x   = (const float*)d_in[3];
  const float* Wa1 = (const float*)d_in[4];  const float* ba1 = (const float*)d_in[5];
  const float* Wa2 = (const float*)d_in[6];  const float* ba2 = (const float*)d_in[7];
  const float* Wa3 = (const float*)d_in[8];  const float* ba3 = (const float*)d_in[9];
  const float* Wagg = (const float*)d_in[10]; const float* bagg = (const float*)d_in[11];
  const float* W1  = (const float*)d_in[12]; const float* b1  = (const float*)d_in[13];
  const float* Wq  = (const float*)d_in[14]; const float* bq  = (const float*)d_in[15];
  const float* Wk  = (const float*)d_in[16]; const float* bk  = (const float*)d_in[17];
  const float* Wv  = (const float*)d_in[18]; const float* bv  = (const float*)d_in[19];
  const float* W2  = (const float*)d_in[20]; const float* b2  = (const float*)d_in[21];

  float* out0 = (float*)d_out;            // [N,16] class softmax
  float* nz   = out0 + N * NC;            // [N,3] mixing weights (output 1)

  float* ws   = (float*)d_ws;
  float* adj  = ws;                       // N*N
  float* Wc   = adj + (size_t)N * N;      // 3*N*3
  float* bz   = Wc + 3 * N * 3;           // 16
  float* xw1  = bz + 16;                  // N*NH  (attn partial 0)
  float* hpre = xw1 + N * NH;             // N*NH  (attn partial 1)
  float* QhT  = hpre + N * NH;            // N*NH  transposed [128][4096]
  float* KhT  = QhT + N * NH;             // N*NH  transposed [128][4096]
  float* Vh   = KhT + N * NH;             // N*NH
  float* Xt   = Vh + N * NH;              // N*NH  (attn partial 7)
  float* xtw2 = Xt + N * NH;              // N*NC
  float* P2   = xtw2 + N * NC;            // 5 extra partials
  float* P3   = P2 + N * NH;
  float* P4   = P3 + N * NH;
  float* P5   = P4 + N * NH;
  float* P6   = P5 + N * NH;
  float* ml   = P6 + N * NH;              // 8*N*2
  float* zp   = QhT;                      // [N][12] partials (dead until k_qkv)

  hipLaunchKernelGGL(k_wc, dim3(48), dim3(256), 0, stream,
                     Wa1, Wa2, Wa3, Wagg, ba1, ba2, ba3, bagg, Wc, bz);
  hipLaunchKernelGGL(k_z4p, dim3(N / 8, 4), dim3(256), 0, stream,
                     A0, A1, A2, Wc, zp);
  hipLaunchKernelGGL(k_nz, dim3(N / 256), dim3(256), 0, stream, zp, bz, nz);
  hipLaunchKernelGGL(k_adj, dim3(N * N / 4 / 256), dim3(256), 0, stream,
                     A0, A1, A2, nz, adj);
  hipLaunchKernelGGL(k_xw1, dim3(N / 8), dim3(128), 0, stream, x, W1, xw1);
  hipLaunchKernelGGL(k_hinit, dim3(N * NH / 256), dim3(256), 0, stream, b1, hpre);
  hipLaunchKernelGGL(k_h, dim3(N / 128, 8), dim3(256), 0, stream, adj, xw1, hpre);
  hipLaunchKernelGGL(k_qkv, dim3(N / 8), dim3(128), 0, stream,
                     hpre, Wq, bq, Wk, bk, Wv, bv, QhT, KhT, Vh);
  hipLaunchKernelGGL(k_attn, dim3(N / 128, CSPLIT), dim3(512), 0, stream,
                     QhT, KhT, Vh, adj, xw1, hpre, P2, P3, P4, P5, P6, Xt, ml);
  hipLaunchKernelGGL(k_comb, dim3(N * NH / 4 / 256), dim3(256), 0, stream,
                     xw1, hpre, P2, P3, P4, P5, P6, Xt, ml, Xt);
  hipLaunchKernelGGL(k_xtw2, dim3(N / 16), dim3(256), 0, stream, Xt, W2, xtw2);
  hipLaunchKernelGGL(k_z, dim3(N / 16), dim3(256), 0, stream, adj, xtw2, b2, out0);
}

// Round 5
// 432.342 us; speedup vs baseline: 5.0017x; 1.1039x over previous
//
#include <hip/hip_runtime.h>
#include <math.h>

#define N 4096
#define NF 512
#define NH 128
#define NC 16
#define CSPLIT 8

// ---------------------------------------------------------------------------
// k_wc: Wc_k[j,c] = sum_t Wa_k[j,t] * Wagg[k*64+t, c]   (3*N*3 values)
// ---------------------------------------------------------------------------
__global__ void k_wc(const float* __restrict__ Wa1, const float* __restrict__ Wa2,
                     const float* __restrict__ Wa3, const float* __restrict__ Wagg,
                     const float* __restrict__ ba1, const float* __restrict__ ba2,
                     const float* __restrict__ ba3, const float* __restrict__ bagg,
                     float* __restrict__ Wc, float* __restrict__ bz) {
  int idx = blockIdx.x * 256 + threadIdx.x;
  if (idx < 3 * N) {
    int k = idx >> 12;
    int j = idx & (N - 1);
    const float* Wa = (k == 0) ? Wa1 : (k == 1) ? Wa2 : Wa3;
    float a0 = 0.f, a1 = 0.f, a2 = 0.f;
    for (int t = 0; t < 64; ++t) {
      float w = Wa[j * 64 + t];
      const float* wg = Wagg + (k * 64 + t) * 3;
      a0 += w * wg[0]; a1 += w * wg[1]; a2 += w * wg[2];
    }
    float* o = Wc + j * 9 + k * 3;
    o[0] = a0; o[1] = a1; o[2] = a2;
  }
  if (blockIdx.x == 0 && threadIdx.x < 3) {
    int c = threadIdx.x;
    float acc = bagg[c];
    for (int t = 0; t < 64; ++t) {
      acc += ba1[t] * Wagg[t * 3 + c]
           + ba2[t] * Wagg[(64 + t) * 3 + c]
           + ba3[t] * Wagg[(128 + t) * 3 + c];
    }
    bz[c] = acc;
  }
}

// ---------------------------------------------------------------------------
// k_z4p: partial z4 over a 1024-column chunk.  Grid (512, 4), 256 threads.
// ---------------------------------------------------------------------------
__global__ __launch_bounds__(256, 4) void k_z4p(
    const float* __restrict__ A0, const float* __restrict__ A1,
    const float* __restrict__ A2, const float* __restrict__ Wc,
    float* __restrict__ zp) {
  __shared__ float red[8][3][4];
  int i0 = blockIdx.x * 8;
  int c0 = blockIdx.y * 1024;
  int tid = threadIdx.x;
  int j4 = c0 + tid * 4;
  float w[36];
#pragma unroll
  for (int q = 0; q < 9; ++q) {
    const float4 v = *(const float4*)&Wc[j4 * 9 + q * 4];
    w[4 * q] = v.x; w[4 * q + 1] = v.y; w[4 * q + 2] = v.z; w[4 * q + 3] = v.w;
  }
  float acc[8][3];
#pragma unroll
  for (int r = 0; r < 8; ++r) { acc[r][0] = 0.f; acc[r][1] = 0.f; acc[r][2] = 0.f; }
#pragma unroll
  for (int r = 0; r < 8; ++r) {
    const float4 a0 = *(const float4*)&A0[(i0 + r) * N + j4];
    const float4 a1 = *(const float4*)&A1[(i0 + r) * N + j4];
    const float4 a2 = *(const float4*)&A2[(i0 + r) * N + j4];
#pragma unroll
    for (int jj = 0; jj < 4; ++jj) {
      float x0 = ((const float*)&a0)[jj];
      float x1 = ((const float*)&a1)[jj];
      float x2 = ((const float*)&a2)[jj];
#pragma unroll
      for (int cc = 0; cc < 3; ++cc)
        acc[r][cc] += x0 * w[jj * 9 + cc] + x1 * w[jj * 9 + 3 + cc]
                    + x2 * w[jj * 9 + 6 + cc];
    }
  }
  int lane = tid & 63, wv = tid >> 6;
#pragma unroll
  for (int r = 0; r < 8; ++r) {
#pragma unroll
    for (int c = 0; c < 3; ++c) {
      float v = acc[r][c];
      v += __shfl_down(v, 32);
      v += __shfl_down(v, 16);
      v += __shfl_down(v, 8);
      v += __shfl_down(v, 4);
      v += __shfl_down(v, 2);
      v += __shfl_down(v, 1);
      if (lane == 0) red[r][c][wv] = v;
    }
  }
  __syncthreads();
  if (tid < 8) {
#pragma unroll
    for (int c = 0; c < 3; ++c) {
      float v = red[tid][c][0] + red[tid][c][1] + red[tid][c][2] + red[tid][c][3];
      zp[(i0 + tid) * 12 + blockIdx.y * 3 + c] = v;
    }
  }
}

// ---------------------------------------------------------------------------
// k_nz: finalize z4 (sum 4 chunk partials + bz) and 3-way softmax -> nz
// ---------------------------------------------------------------------------
__global__ void k_nz(const float* __restrict__ zp, const float* __restrict__ bz,
                     float* __restrict__ nz) {
  int row = blockIdx.x * 256 + threadIdx.x;
  const float* p = zp + row * 12;
  float z0 = p[0] + p[3] + p[6] + p[9] + bz[0];
  float z1 = p[1] + p[4] + p[7] + p[10] + bz[1];
  float z2 = p[2] + p[5] + p[8] + p[11] + bz[2];
  float m = fmaxf(z0, fmaxf(z1, z2));
  float e0 = __expf(z0 - m), e1 = __expf(z1 - m), e2 = __expf(z2 - m);
  float s = e0 + e1 + e2;
  float* o = nz + row * 3;
  o[0] = e0 / s; o[1] = e1 / s; o[2] = e2 / s;
}

// ---------------------------------------------------------------------------
// k_adj: adj[i,j] = A0*nz[j,0] + A1*nz[j,1] + A2*nz[j,2]  (column-broadcast)
// ---------------------------------------------------------------------------
__global__ void k_adj(const float* __restrict__ A0, const float* __restrict__ A1,
                      const float* __restrict__ A2, const float* __restrict__ nz,
                      float* __restrict__ adj) {
  int idx = blockIdx.x * 256 + threadIdx.x;
  int i = idx >> 10;
  int j4 = (idx & 1023) << 2;
  int base = i * N + j4;
  const float4 a0 = *(const float4*)&A0[base];
  const float4 a1 = *(const float4*)&A1[base];
  const float4 a2 = *(const float4*)&A2[base];
  const float4 n0 = *(const float4*)&nz[j4 * 3];
  const float4 n1 = *(const float4*)&nz[j4 * 3 + 4];
  const float4 n2 = *(const float4*)&nz[j4 * 3 + 8];
  float4 o;
  o.x = a0.x * n0.x + a1.x * n0.y + a2.x * n0.z;
  o.y = a0.y * n0.w + a1.y * n1.x + a2.y * n1.y;
  o.z = a0.z * n1.z + a1.z * n1.w + a2.z * n2.x;
  o.w = a0.w * n2.y + a1.w * n2.z + a2.w * n2.w;
  *(float4*)&adj[base] = o;
}

// ---------------------------------------------------------------------------
// k_xw1: xw1 = x @ W1.  8 rows/block, 512 blocks, 128 threads.
// ---------------------------------------------------------------------------
__global__ void k_xw1(const float* __restrict__ x, const float* __restrict__ W1,
                      float* __restrict__ xw1) {
  __shared__ float xs[8][NF];
  int i0 = blockIdx.x * 8;
  int tid = threadIdx.x;
  for (int l = tid; l < 8 * NF; l += 128) {
    int r = l >> 9, k = l & (NF - 1);
    xs[r][k] = x[(i0 + r) * NF + k];
  }
  __syncthreads();
  float acc[8];
#pragma unroll
  for (int r = 0; r < 8; ++r) acc[r] = 0.f;
#pragma unroll 4
  for (int k = 0; k < NF; ++k) {
    float w = W1[k * NH + tid];
#pragma unroll
    for (int r = 0; r < 8; ++r) acc[r] += xs[r][k] * w;
  }
  for (int r = 0; r < 8; ++r) xw1[(i0 + r) * NH + tid] = acc[r];
}

// ---------------------------------------------------------------------------
// k_h: hp_chunk = adj[:, chunk] @ xw1[chunk, :]   (no atomics; 4 partials)
// Grid (64, 4) = 256 blocks, 256 threads. BM=64, K-chunk=1024, BK=64, BN=128.
// Per-thread 4 rows x 8 cols. LDS: adjT[64][68] + xw1s[64][132] = 51 KB.
// ---------------------------------------------------------------------------
__global__ __launch_bounds__(256) void k_h(const float* __restrict__ adj,
                                           const float* __restrict__ xw1,
                                           float* __restrict__ hp0,
                                           float* __restrict__ hp1,
                                           float* __restrict__ hp2,
                                           float* __restrict__ hp3) {
  __shared__ float adjT[64 * 68];
  __shared__ float xw1s[64 * 132];
  int i0 = blockIdx.x * 64;
  int kbase = blockIdx.y * 1024;
  float* hp = (blockIdx.y == 0) ? hp0 : (blockIdx.y == 1) ? hp1
            : (blockIdx.y == 2) ? hp2 : hp3;
  int tid = threadIdx.x;
  int ty = tid >> 4, tx = tid & 15;      // rows 4ty..+3; cols {4tx, 64+4tx}..+3
  float acc[4][8];
#pragma unroll
  for (int i = 0; i < 4; ++i)
#pragma unroll
    for (int c = 0; c < 8; ++c) acc[i][c] = 0.f;

  for (int t = 0; t < 16; ++t) {
    int k0 = kbase + t * 64;
    __syncthreads();                     // prior compute done
    // stage adj block transposed: 64 rows x 64 k -> adjT[k][r]
#pragma unroll
    for (int s = 0; s < 4; ++s) {
      int f4 = tid + 256 * s;
      int r = f4 >> 4, k4 = (f4 & 15) << 2;
      const float4 v = *(const float4*)&adj[(i0 + r) * N + k0 + k4];
      adjT[(k4 + 0) * 68 + r] = v.x;
      adjT[(k4 + 1) * 68 + r] = v.y;
      adjT[(k4 + 2) * 68 + r] = v.z;
      adjT[(k4 + 3) * 68 + r] = v.w;
    }
    // stage xw1 block: 64 k x 128 c
#pragma unroll
    for (int s = 0; s < 8; ++s) {
      int f4 = tid + 256 * s;
      int k = f4 >> 5, c4 = (f4 & 31) << 2;
      *(float4*)&xw1s[k * 132 + c4] = *(const float4*)&xw1[(k0 + k) * NH + c4];
    }
    __syncthreads();
#pragma unroll 4
    for (int k = 0; k < 64; ++k) {
      const float4 a = *(const float4*)&adjT[k * 68 + 4 * ty];
      const float4 w0 = *(const float4*)&xw1s[k * 132 + 4 * tx];
      const float4 w1 = *(const float4*)&xw1s[k * 132 + 64 + 4 * tx];
#pragma unroll
      for (int i = 0; i < 4; ++i) {
        float ai = ((const float*)&a)[i];
        acc[i][0] += ai * w0.x; acc[i][1] += ai * w0.y;
        acc[i][2] += ai * w0.z; acc[i][3] += ai * w0.w;
        acc[i][4] += ai * w1.x; acc[i][5] += ai * w1.y;
        acc[i][6] += ai * w1.z; acc[i][7] += ai * w1.w;
      }
    }
  }
#pragma unroll
  for (int i = 0; i < 4; ++i) {
    int row = i0 + 4 * ty + i;
    float4 o0 = {acc[i][0], acc[i][1], acc[i][2], acc[i][3]};
    float4 o1 = {acc[i][4], acc[i][5], acc[i][6], acc[i][7]};
    *(float4*)&hp[row * NH + 4 * tx] = o0;
    *(float4*)&hp[row * NH + 64 + 4 * tx] = o1;
  }
}

// ---------------------------------------------------------------------------
// k_qkv: h = relu(hp0+hp1+hp2+hp3+b1); QhT/KhT (d-major) and Vh (row-major).
// 8 rows/block, 512 blocks, 128 threads.
// ---------------------------------------------------------------------------
__global__ void k_qkv(const float* __restrict__ hp0, const float* __restrict__ hp1,
                      const float* __restrict__ hp2, const float* __restrict__ hp3,
                      const float* __restrict__ b1,
                      const float* __restrict__ Wq, const float* __restrict__ bq,
                      const float* __restrict__ Wk, const float* __restrict__ bk,
                      const float* __restrict__ Wv, const float* __restrict__ bv,
                      float* __restrict__ QhT, float* __restrict__ KhT,
                      float* __restrict__ Vh) {
  __shared__ float hs[8][NH];
  int i0 = blockIdx.x * 8;
  int tid = threadIdx.x;
#pragma unroll
  for (int s = 0; s < 2; ++s) {
    int f4 = tid + 128 * s;                 // 256 float4s = 8x128
    int r = f4 >> 5, k4 = (f4 & 31) << 2;
    int gi = (i0 + r) * NH + k4;
    const float4 v0 = *(const float4*)&hp0[gi];
    const float4 v1 = *(const float4*)&hp1[gi];
    const float4 v2 = *(const float4*)&hp2[gi];
    const float4 v3 = *(const float4*)&hp3[gi];
    const float4 bv = *(const float4*)&b1[k4];
    hs[r][k4 + 0] = fmaxf(v0.x + v1.x + v2.x + v3.x + bv.x, 0.f);
    hs[r][k4 + 1] = fmaxf(v0.y + v1.y + v2.y + v3.y + bv.y, 0.f);
    hs[r][k4 + 2] = fmaxf(v0.z + v1.z + v2.z + v3.z + bv.z, 0.f);
    hs[r][k4 + 3] = fmaxf(v0.w + v1.w + v2.w + v3.w + bv.w, 0.f);
  }
  __syncthreads();
  float aq[8], ak[8], av[8];
#pragma unroll
  for (int r = 0; r < 8; ++r) { aq[r] = 0.f; ak[r] = 0.f; av[r] = 0.f; }
#pragma unroll 4
  for (int k = 0; k < NH; ++k) {
    float wq = Wq[k * NH + tid];
    float wk = Wk[k * NH + tid];
    float wv = Wv[k * NH + tid];
#pragma unroll
    for (int r = 0; r < 8; ++r) {
      float h = hs[r][k];
      aq[r] += h * wq; ak[r] += h * wk; av[r] += h * wv;
    }
  }
  float bqv = bq[tid], bkv = bk[tid], bvv = bv[tid];
#pragma unroll
  for (int r = 0; r < 8; r += 4) {
    float4 q = {aq[r] + bqv, aq[r + 1] + bqv, aq[r + 2] + bqv, aq[r + 3] + bqv};
    float4 k4 = {ak[r] + bkv, ak[r + 1] + bkv, ak[r + 2] + bkv, ak[r + 3] + bkv};
    *(float4*)&QhT[tid * N + i0 + r] = q;
    *(float4*)&KhT[tid * N + i0 + r] = k4;
  }
  for (int r = 0; r < 8; ++r) Vh[(i0 + r) * NH + tid] = av[r] + bvv;
}

// ---------------------------------------------------------------------------
// k_attn: partial flash attention over a 512-column chunk.
// Grid (32, 8); 512 threads. BM=128 rows, BN=64 per tile (8 tiles).
// ---------------------------------------------------------------------------
__global__ __launch_bounds__(512) void k_attn(
    const float* __restrict__ QhT, const float* __restrict__ KhT,
    const float* __restrict__ Vh, const float* __restrict__ adj,
    float* __restrict__ xp0, float* __restrict__ xp1, float* __restrict__ xp2,
    float* __restrict__ xp3, float* __restrict__ xp4, float* __restrict__ xp5,
    float* __restrict__ xp6, float* __restrict__ xp7,
    float* __restrict__ ml) {
  __shared__ float Qs[128 * 128];
  __shared__ float Ks[128 * 68];
  __shared__ float Vs[64 * 128];
  int i0 = blockIdx.x * 128;
  int cid = blockIdx.y;
  int tid = threadIdx.x;
  int ty = tid >> 4, tx = tid & 15;
  float* xp = (cid < 4) ? ((cid < 2) ? (cid == 0 ? xp0 : xp1) : (cid == 2 ? xp2 : xp3))
                        : ((cid < 6) ? (cid == 4 ? xp4 : xp5) : (cid == 6 ? xp6 : xp7));

#pragma unroll
  for (int s = 0; s < 8; ++s) {
    int f4 = tid + 512 * s;
    int d = f4 >> 5, r4 = (f4 & 31) << 2;
    *(float4*)&Qs[d * 128 + r4] = *(const float4*)&QhT[d * N + i0 + r4];
  }

  float m[4], l[4], X[4][8];
#pragma unroll
  for (int i = 0; i < 4; ++i) {
    m[i] = -3.0e38f; l[i] = 0.f;
#pragma unroll
    for (int c = 0; c < 8; ++c) X[i][c] = 0.f;
  }

  for (int jt = 0; jt < 8; ++jt) {
    int j0g = cid * (N / CSPLIT) + jt * 64;
    float4 adjv[4];
#pragma unroll
    for (int i = 0; i < 4; ++i)
      adjv[i] = *(const float4*)&adj[(i0 + 4 * ty + i) * N + j0g + 4 * tx];
    __syncthreads();
#pragma unroll
    for (int s = 0; s < 4; ++s) {
      int f4 = tid + 512 * s;
      int d = f4 >> 4, j4 = (f4 & 15) << 2;
      *(float4*)&Ks[d * 68 + j4] = *(const float4*)&KhT[d * N + j0g + j4];
    }
#pragma unroll
    for (int s = 0; s < 4; ++s) {
      int f4 = tid + 512 * s;
      int j = f4 >> 5, d4 = (f4 & 31) << 2;
      *(float4*)&Vs[j * 128 + d4] = *(const float4*)&Vh[(j0g + j) * NH + d4];
    }
    __syncthreads();

    float sm[4][4];
#pragma unroll
    for (int i = 0; i < 4; ++i)
#pragma unroll
      for (int c = 0; c < 4; ++c) sm[i][c] = 0.f;
#pragma unroll 8
    for (int k = 0; k < 128; ++k) {
      const float4 qv = *(const float4*)&Qs[k * 128 + 4 * ty];
      const float4 kv = *(const float4*)&Ks[k * 68 + 4 * tx];
#pragma unroll
      for (int i = 0; i < 4; ++i) {
        float q = ((const float*)&qv)[i];
        sm[i][0] += q * kv.x; sm[i][1] += q * kv.y;
        sm[i][2] += q * kv.z; sm[i][3] += q * kv.w;
      }
    }
    float p[4][4];
#pragma unroll
    for (int i = 0; i < 4; ++i) {
      float a0 = sm[i][0] * adjv[i].x;
      float a1 = sm[i][1] * adjv[i].y;
      float a2 = sm[i][2] * adjv[i].z;
      float a3 = sm[i][3] * adjv[i].w;
      float t = fmaxf(fmaxf(a0, a1), fmaxf(a2, a3));
      t = fmaxf(t, __shfl_xor(t, 1));
      t = fmaxf(t, __shfl_xor(t, 2));
      t = fmaxf(t, __shfl_xor(t, 4));
      t = fmaxf(t, __shfl_xor(t, 8));
      float mn = fmaxf(m[i], t);
      float sc = __expf(m[i] - mn);
      p[i][0] = __expf(a0 - mn); p[i][1] = __expf(a1 - mn);
      p[i][2] = __expf(a2 - mn); p[i][3] = __expf(a3 - mn);
      float ps = p[i][0] + p[i][1] + p[i][2] + p[i][3];
      ps += __shfl_xor(ps, 1);
      ps += __shfl_xor(ps, 2);
      ps += __shfl_xor(ps, 4);
      ps += __shfl_xor(ps, 8);
      l[i] = l[i] * sc + ps;
      m[i] = mn;
#pragma unroll
      for (int c = 0; c < 8; ++c) X[i][c] *= sc;
    }
    __syncthreads();
#pragma unroll
    for (int i = 0; i < 4; ++i) {
      float4 pv = {p[i][0], p[i][1], p[i][2], p[i][3]};
      *(float4*)&Ks[(4 * ty + i) * 68 + 4 * tx] = pv;
    }
    __syncthreads();

#pragma unroll 2
    for (int j0 = 0; j0 < 64; j0 += 4) {
      float4 pr[4];
#pragma unroll
      for (int i = 0; i < 4; ++i)
        pr[i] = *(const float4*)&Ks[(4 * ty + i) * 68 + j0];
#pragma unroll
      for (int jj = 0; jj < 4; ++jj) {
        const float4 v0 = *(const float4*)&Vs[(j0 + jj) * 128 + 4 * tx];
        const float4 v1 = *(const float4*)&Vs[(j0 + jj) * 128 + 64 + 4 * tx];
#pragma unroll
        for (int i = 0; i < 4; ++i) {
          float pj = ((const float*)&pr[i])[jj];
          X[i][0] += pj * v0.x; X[i][1] += pj * v0.y;
          X[i][2] += pj * v0.z; X[i][3] += pj * v0.w;
          X[i][4] += pj * v1.x; X[i][5] += pj * v1.y;
          X[i][6] += pj * v1.z; X[i][7] += pj * v1.w;
        }
      }
    }
  }

#pragma unroll
  for (int i = 0; i < 4; ++i) {
    int row = i0 + 4 * ty + i;
    float4 o0 = {X[i][0], X[i][1], X[i][2], X[i][3]};
    float4 o1 = {X[i][4], X[i][5], X[i][6], X[i][7]};
    *(float4*)&xp[row * NH + 4 * tx] = o0;
    *(float4*)&xp[row * NH + 64 + 4 * tx] = o1;
    if (tx == 0) {
      ml[(cid * N + row) * 2 + 0] = m[i];
      ml[(cid * N + row) * 2 + 1] = l[i];
    }
  }
}

// ---------------------------------------------------------------------------
// k_comb: merge 8 chunk-partials, normalize, relu -> Xt
// ---------------------------------------------------------------------------
__global__ void k_comb(const float* __restrict__ xp0, const float* __restrict__ xp1,
                       const float* __restrict__ xp2, const float* __restrict__ xp3,
                       const float* __restrict__ xp4, const float* __restrict__ xp5,
                       const float* __restrict__ xp6, const float* __restrict__ xp7,
                       const float* __restrict__ ml, float* __restrict__ Xt) {
  int idx = blockIdx.x * 256 + threadIdx.x;
  int r = idx >> 5, d4 = (idx & 31) << 2;
  float mm[8], ll[8];
#pragma unroll
  for (int c = 0; c < 8; ++c) {
    mm[c] = ml[(c * N + r) * 2 + 0];
    ll[c] = ml[(c * N + r) * 2 + 1];
  }
  float ms = mm[0];
#pragma unroll
  for (int c = 1; c < 8; ++c) ms = fmaxf(ms, mm[c]);
  float e[8], den = 0.f;
#pragma unroll
  for (int c = 0; c < 8; ++c) { e[c] = __expf(mm[c] - ms); den += e[c] * ll[c]; }
  float inv = 1.f / den;
  const float4 a0 = *(const float4*)&xp0[r * NH + d4];
  const float4 a1 = *(const float4*)&xp1[r * NH + d4];
  const float4 a2 = *(const float4*)&xp2[r * NH + d4];
  const float4 a3 = *(const float4*)&xp3[r * NH + d4];
  const float4 a4 = *(const float4*)&xp4[r * NH + d4];
  const float4 a5 = *(const float4*)&xp5[r * NH + d4];
  const float4 a6 = *(const float4*)&xp6[r * NH + d4];
  const float4 a7 = *(const float4*)&xp7[r * NH + d4];
  float4 o;
  o.x = a0.x * e[0] + a1.x * e[1] + a2.x * e[2] + a3.x * e[3]
      + a4.x * e[4] + a5.x * e[5] + a6.x * e[6] + a7.x * e[7];
  o.y = a0.y * e[0] + a1.y * e[1] + a2.y * e[2] + a3.y * e[3]
      + a4.y * e[4] + a5.y * e[5] + a6.y * e[6] + a7.y * e[7];
  o.z = a0.z * e[0] + a1.z * e[1] + a2.z * e[2] + a3.z * e[3]
      + a4.z * e[4] + a5.z * e[5] + a6.z * e[6] + a7.z * e[7];
  o.w = a0.w * e[0] + a1.w * e[1] + a2.w * e[2] + a3.w * e[3]
      + a4.w * e[4] + a5.w * e[5] + a6.w * e[6] + a7.w * e[7];
  o.x = fmaxf(o.x * inv, 0.f); o.y = fmaxf(o.y * inv, 0.f);
  o.z = fmaxf(o.z * inv, 0.f); o.w = fmaxf(o.w * inv, 0.f);
  *(float4*)&Xt[r * NH + d4] = o;
}

// ---------------------------------------------------------------------------
// k_xtw2: xtw2 = Xt @ W2.  16 rows/block, 256 blocks, 256 threads.
// Xt tile (padded 132) + W2 staged in LDS; one (row, class) per thread.
// ---------------------------------------------------------------------------
__global__ __launch_bounds__(256) void k_xtw2(const float* __restrict__ Xt,
                                              const float* __restrict__ W2,
                                              float* __restrict__ xtw2) {
  __shared__ float xs[16 * 132];
  __shared__ float w2s[NH * NC];
  int i0 = blockIdx.x * 16;
  int tid = threadIdx.x;
#pragma unroll
  for (int s = 0; s < 2; ++s) {
    int f4 = tid + 256 * s;                  // 512 float4 = 16x128
    int r = f4 >> 5, k4 = (f4 & 31) << 2;
    const float4 v = *(const float4*)&Xt[(i0 + r) * NH + k4];
    *(float4*)&xs[r * 132 + k4] = v;
    *(float4*)&w2s[f4 * 4] = *(const float4*)&W2[f4 * 4];
  }
  __syncthreads();
  int r = tid >> 4, c = tid & 15;
  float acc = 0.f;
#pragma unroll 8
  for (int k = 0; k < NH; ++k)
    acc += xs[r * 132 + k] * w2s[k * NC + c];
  xtw2[(i0 + r) * NC + c] = acc;
}

// ---------------------------------------------------------------------------
// k_z: z = adj @ xtw2 + b2; out = rowsoftmax(z).
// ---------------------------------------------------------------------------
__global__ __launch_bounds__(256) void k_z(const float* __restrict__ adj,
                                           const float* __restrict__ xtw2,
                                           const float* __restrict__ b2,
                                           float* __restrict__ out) {
  __shared__ float xwsT[16 * 68];
  int i0 = blockIdx.x * 16;
  int tid = threadIdx.x;
  int ty = tid >> 6, cg = (tid >> 4) & 3, jg = tid & 15;
  int jr = tid >> 2, cq = tid & 3;
  float acc[4][4];
#pragma unroll
  for (int i = 0; i < 4; ++i)
#pragma unroll
    for (int c = 0; c < 4; ++c) acc[i][c] = 0.f;

  for (int j0 = 0; j0 < N; j0 += 64) {
    float4 av[4];
#pragma unroll
    for (int i = 0; i < 4; ++i)
      av[i] = *(const float4*)&adj[(i0 + 4 * ty + i) * N + j0 + 4 * jg];
    const float4 xv = *(const float4*)&xtw2[(j0 + jr) * NC + 4 * cq];
    __syncthreads();
    xwsT[(4 * cq + 0) * 68 + jr] = xv.x;
    xwsT[(4 * cq + 1) * 68 + jr] = xv.y;
    xwsT[(4 * cq + 2) * 68 + jr] = xv.z;
    xwsT[(4 * cq + 3) * 68 + jr] = xv.w;
    __syncthreads();
#pragma unroll
    for (int c = 0; c < 4; ++c) {
      const float4 wv = *(const float4*)&xwsT[(4 * cg + c) * 68 + 4 * jg];
#pragma unroll
      for (int i = 0; i < 4; ++i)
        acc[i][c] += av[i].x * wv.x + av[i].y * wv.y
                   + av[i].z * wv.z + av[i].w * wv.w;
    }
  }
#pragma unroll
  for (int i = 0; i < 4; ++i)
#pragma unroll
    for (int c = 0; c < 4; ++c) {
      float v = acc[i][c];
      v += __shfl_xor(v, 1);
      v += __shfl_xor(v, 2);
      v += __shfl_xor(v, 4);
      v += __shfl_xor(v, 8);
      acc[i][c] = v;
    }
  float bv0 = b2[4 * cg + 0], bv1 = b2[4 * cg + 1];
  float bv2 = b2[4 * cg + 2], bv3 = b2[4 * cg + 3];
#pragma unroll
  for (int i = 0; i < 4; ++i) {
    float z0 = acc[i][0] + bv0, z1 = acc[i][1] + bv1;
    float z2 = acc[i][2] + bv2, z3 = acc[i][3] + bv3;
    float mv = fmaxf(fmaxf(z0, z1), fmaxf(z2, z3));
    mv = fmaxf(mv, __shfl_xor(mv, 16));
    mv = fmaxf(mv, __shfl_xor(mv, 32));
    float e0 = __expf(z0 - mv), e1 = __expf(z1 - mv);
    float e2 = __expf(z2 - mv), e3 = __expf(z3 - mv);
    float s = e0 + e1 + e2 + e3;
    s += __shfl_xor(s, 16);
    s += __shfl_xor(s, 32);
    if (jg == 0) {
      float4 o = {e0 / s, e1 / s, e2 / s, e3 / s};
      *(float4*)&out[(i0 + 4 * ty + i) * NC + 4 * cg] = o;
    }
  }
}

// ---------------------------------------------------------------------------
extern "C" void kernel_launch(void* const* d_in, const int* in_sizes, int n_in,
                              void* d_out, int out_size, void* d_ws, size_t ws_size,
                              hipStream_t stream) {
  const float* A0  = (const float*)d_in[0];
  const float* A1  = (const float*)d_in[1];
  const float* A2  = (const float*)d_in[2];
  const float* x   = (const float*)d_in[3];
  const float* Wa1 = (const float*)d_in[4];  const float* ba1 = (const float*)d_in[5];
  const float* Wa2 = (const float*)d_in[6];  const float* ba2 = (const float*)d_in[7];
  const float* Wa3 = (const float*)d_in[8];  const float* ba3 = (const float*)d_in[9];
  const float* Wagg = (const float*)d_in[10]; const float* bagg = (const float*)d_in[11];
  const float* W1  = (const float*)d_in[12]; const float* b1  = (const float*)d_in[13];
  const float* Wq  = (const float*)d_in[14]; const float* bq  = (const float*)d_in[15];
  const float* Wk  = (const float*)d_in[16]; const float* bk  = (const float*)d_in[17];
  const float* Wv  = (const float*)d_in[18]; const float* bv  = (const float*)d_in[19];
  const float* W2  = (const float*)d_in[20]; const float* b2  = (const float*)d_in[21];

  float* out0 = (float*)d_out;            // [N,16] class softmax
  float* nz   = out0 + N * NC;            // [N,3] mixing weights (output 1)

  float* ws   = (float*)d_ws;
  float* adj  = ws;                       // N*N
  float* Wc   = adj + (size_t)N * N;      // 3*N*3
  float* bz   = Wc + 3 * N * 3;           // 16
  float* xw1  = bz + 16;                  // N*NH  (attn partial 0)
  float* hpre = xw1 + N * NH;             // N*NH  (h partial 0 / attn partial 1)
  float* QhT  = hpre + N * NH;            // N*NH  transposed [128][4096]
  float* KhT  = QhT + N * NH;             // N*NH  transposed [128][4096]
  float* Vh   = KhT + N * NH;             // N*NH
  float* Xt   = Vh + N * NH;              // N*NH  (attn partial 7)
  float* xtw2 = Xt + N * NH;              // N*NC
  float* P2   = xtw2 + N * NC;            // h partial 1 / attn partial 2
  float* P3   = P2 + N * NH;              // h partial 2 / attn partial 3
  float* P4   = P3 + N * NH;              // h partial 3 / attn partial 4
  float* P5   = P4 + N * NH;
  float* P6   = P5 + N * NH;
  float* ml   = P6 + N * NH;              // 8*N*2
  float* zp   = QhT;                      // [N][12] partials (dead until k_qkv)

  hipLaunchKernelGGL(k_wc, dim3(48), dim3(256), 0, stream,
                     Wa1, Wa2, Wa3, Wagg, ba1, ba2, ba3, bagg, Wc, bz);
  hipLaunchKernelGGL(k_z4p, dim3(N / 8, 4), dim3(256), 0, stream,
                     A0, A1, A2, Wc, zp);
  hipLaunchKernelGGL(k_nz, dim3(N / 256), dim3(256), 0, stream, zp, bz, nz);
  hipLaunchKernelGGL(k_adj, dim3(N * N / 4 / 256), dim3(256), 0, stream,
                     A0, A1, A2, nz, adj);
  hipLaunchKernelGGL(k_xw1, dim3(N / 8), dim3(128), 0, stream, x, W1, xw1);
  hipLaunchKernelGGL(k_h, dim3(N / 64, 4), dim3(256), 0, stream,
                     adj, xw1, hpre, P2, P3, P4);
  hipLaunchKernelGGL(k_qkv, dim3(N / 8), dim3(128), 0, stream,
                     hpre, P2, P3, P4, b1, Wq, bq, Wk, bk, Wv, bv, QhT, KhT, Vh);
  hipLaunchKernelGGL(k_attn, dim3(N / 128, CSPLIT), dim3(512), 0, stream,
                     QhT, KhT, Vh, adj, xw1, hpre, P2, P3, P4, P5, P6, Xt, ml);
  hipLaunchKernelGGL(k_comb, dim3(N * NH / 4 / 256), dim3(256), 0, stream,
                     xw1, hpre, P2, P3, P4, P5, P6, Xt, ml, Xt);
  hipLaunchKernelGGL(k_xtw2, dim3(N / 16), dim3(256), 0, stream, Xt, W2, xtw2);
  hipLaunchKernelGGL(k_z, dim3(N / 16), dim3(256), 0, stream, adj, xtw2, b2, out0);
}